// Round 3
// baseline (303.782 us; speedup 1.0000x reference)
//
#include <hip/hip_runtime.h>
#include <hip/hip_bf16.h>
#include <cstdint>
#include <cstddef>

#define T_DIM 1024
#define S_DIM 1024
#define N_HEADS 32
#define D_HEAD 128

typedef __attribute__((ext_vector_type(8))) short short8;
typedef __attribute__((ext_vector_type(4))) float floatx4;

__device__ inline int pack_bf16(float a, float b) {
    __hip_bfloat162 h = __float22bfloat162_rn(make_float2(a, b));
    int r; __builtin_memcpy(&r, &h, 4); return r;
}
__device__ inline ushort f2b(float x) {
    __hip_bfloat16 h = __float2bfloat16(x);
    ushort u; __builtin_memcpy(&u, &h, 2); return u;
}
__device__ inline float b2f(ushort u) {
    unsigned int v = ((unsigned int)u) << 16;
    float f; __builtin_memcpy(&f, &v, 4); return f;
}
__device__ inline uint ext16(const uint4& u, int sp) {
    const uint* p = (const uint*)&u;
    return (p[sp >> 1] >> ((sp & 1) * 16)) & 0xffffu;
}

// ---------------------------------------------------------------------------
// Vt[n][d][s] bf16 <- V[n][s][d] fp32.  64s x 128d tile per block. (unchanged)
// ---------------------------------------------------------------------------
__global__ __launch_bounds__(256) void vt_kernel(const float* __restrict__ V,
                                                 ushort* __restrict__ Vt) {
    const int s0 = blockIdx.x * 64;
    const int n  = blockIdx.y;
    __shared__ float lds[128 * 65];

    const int tid = threadIdx.x;
    const float* Vn = V + ((size_t)n * S_DIM + s0) * D_HEAD;

    #pragma unroll
    for (int it = 0; it < 8; ++it) {
        int idx = tid + it * 256;
        int d4 = idx & 31, s = idx >> 5;
        float4 v = *(const float4*)(Vn + (size_t)s * D_HEAD + d4 * 4);
        lds[(d4 * 4 + 0) * 65 + s] = v.x;
        lds[(d4 * 4 + 1) * 65 + s] = v.y;
        lds[(d4 * 4 + 2) * 65 + s] = v.z;
        lds[(d4 * 4 + 3) * 65 + s] = v.w;
    }
    __syncthreads();

    ushort* Vtn = Vt + (size_t)n * D_HEAD * S_DIM;
    #pragma unroll
    for (int it = 0; it < 4; ++it) {
        int idx = tid + it * 256;
        int sg = idx & 7, d = idx >> 3;
        const float* src = &lds[d * 65 + sg * 8];
        int4 o;
        o.x = pack_bf16(src[0], src[1]);
        o.y = pack_bf16(src[2], src[3]);
        o.z = pack_bf16(src[4], src[5]);
        o.w = pack_bf16(src[6], src[7]);
        *(int4*)&Vtn[(size_t)d * S_DIM + s0 + sg * 8] = o;
    }
}

// ---------------------------------------------------------------------------
// K1: logits (bf16) via MFMA, 64x64 causal tiles. (unchanged)
// ---------------------------------------------------------------------------
__global__ __launch_bounds__(256, 2) void qk_mfma(const float* __restrict__ Q,
                                                  const float* __restrict__ K,
                                                  ushort* __restrict__ Lb) {
    const int st = blockIdx.x;
    const int tt = blockIdx.y;
    const int n  = blockIdx.z;
    if (st > tt) return;

    __shared__ int Qt[64 * 64];
    __shared__ int Kt[64 * 64];

    const int tid = threadIdx.x;
    const int wv = tid >> 6, ln = tid & 63;
    const int frow = ln & 15, quad = ln >> 4;

    const float* Qn = Q + ((size_t)n * T_DIM + (size_t)tt * 64) * D_HEAD;
    const float* Kn = K + ((size_t)n * S_DIM + (size_t)st * 64) * D_HEAD;

    #pragma unroll
    for (int rep = 0; rep < 8; ++rep) {
        int idx = tid + rep * 256;
        int row = idx >> 5;
        int c4  = (idx & 31) * 4;
        int p   = c4 >> 1;
        int kb  = p >> 4, w = p & 15;
        int swz = 4 * (row & 3);
        float4 q = *(const float4*)(Qn + (size_t)row * D_HEAD + c4);
        int2 qv; qv.x = pack_bf16(q.x, q.y); qv.y = pack_bf16(q.z, q.w);
        *(int2*)&Qt[row * 64 + kb * 16 + (w ^ swz)] = qv;
        float4 k = *(const float4*)(Kn + (size_t)row * D_HEAD + c4);
        int2 kv; kv.x = pack_bf16(k.x, k.y); kv.y = pack_bf16(k.z, k.w);
        *(int2*)&Kt[row * 64 + kb * 16 + (w ^ swz)] = kv;
    }
    __syncthreads();

    const int swz = 4 * (frow & 3);
    floatx4 acc[4] = {};
    #pragma unroll
    for (int kb = 0; kb < 4; ++kb) {
        const short8 af = *(const short8*)&Qt[(wv * 16 + frow) * 64 + kb * 16 + ((quad * 4) ^ swz)];
        #pragma unroll
        for (int si = 0; si < 4; ++si) {
            const short8 bf = *(const short8*)&Kt[(si * 16 + frow) * 64 + kb * 16 + ((quad * 4) ^ swz)];
            acc[si] = __builtin_amdgcn_mfma_f32_16x16x32_bf16(af, bf, acc[si], 0, 0, 0);
        }
    }
    __syncthreads();                    // Qt dead -> reuse as output tile

    ushort* Ot = (ushort*)Qt;           // [64][72] bf16
    #pragma unroll
    for (int si = 0; si < 4; ++si)
        #pragma unroll
        for (int r = 0; r < 4; ++r)
            Ot[(wv * 16 + quad * 4 + r) * 72 + si * 16 + frow] = f2b(acc[si][r]);
    __syncthreads();

    #pragma unroll
    for (int it = 0; it < 2; ++it) {
        int idx = tid + it * 256;
        int row = idx >> 3, col = idx & 7;
        int4 v = *(const int4*)&Ot[row * 72 + col * 8];
        *(int4*)&Lb[((size_t)n * T_DIM + tt * 64 + row) * S_DIM + st * 64 + col * 8] = v;
    }
}

// ---------------------------------------------------------------------------
// Precompute all four 32x32 mixing-matrix families in one launch. (unchanged)
// ---------------------------------------------------------------------------
__global__ __launch_bounds__(256) void mat4_kernel(
        const float* __restrict__ sw_pre,  const float* __restrict__ qw1_pre,
        const float* __restrict__ qw2_pre, const float* __restrict__ qdd_pre,
        const float* __restrict__ kw1_pre, const float* __restrict__ kw2_pre,
        const float* __restrict__ kdd_pre,
        const float* __restrict__ sw_post,  const float* __restrict__ qw1_post,
        const float* __restrict__ qw2_post, const float* __restrict__ qdd_post,
        const float* __restrict__ kw1_post, const float* __restrict__ kw2_post,
        const float* __restrict__ kdd_post,
        ushort* __restrict__ mats) {
    const float *sw, *w1, *w2, *dd;
    float idadd;
    switch (blockIdx.y) {
        case 0:  sw = sw_pre;  w1 = qw1_pre;  w2 = qw2_pre;  dd = qdd_pre;  idadd = 1.0f; break;
        case 1:  sw = nullptr; w1 = kw1_pre;  w2 = kw2_pre;  dd = kdd_pre;  idadd = 0.0f; break;
        case 2:  sw = sw_post; w1 = qw1_post; w2 = qw2_post; dd = qdd_post; idadd = 1.0f; break;
        default: sw = nullptr; w1 = kw1_post; w2 = kw2_post; dd = kdd_post; idadd = 0.0f; break;
    }
    ushort* out = mats + (size_t)blockIdx.y * 1024 * 1024;

    const int t = blockIdx.x;
    const int tid = threadIdx.x;
    const int m = tid >> 3;
    const int n0 = (tid & 7) * 4;

    const float w2m0 = w2[t * 64 + m];
    const float w2m1 = w2[t * 64 + 32 + m];
    const float ddm  = dd[t * 32 + m];

    float v[4];
    #pragma unroll
    for (int j = 0; j < 4; ++j) {
        int n = n0 + j;
        float r = w1[t * 64 + n] * w2m0 + w1[t * 64 + 32 + n] * w2m1;
        if (sw) r += sw[n * 32 + m];
        if (n == m) r += idadd + ddm;
        v[j] = r;
    }
    int p0 = pack_bf16(v[0], v[1]);
    int p1 = pack_bf16(v[2], v[3]);
    int2 st = make_int2(p0, p1);
    *(int2*)&out[(size_t)t * 1024 + m * 32 + n0] = st;
}

// ---------------------------------------------------------------------------
// rowstat: per-(n,t) softmax stats. One wave per row, 4 rows/block. (unchanged)
// ---------------------------------------------------------------------------
__global__ __launch_bounds__(256) void rowstat(const ushort* __restrict__ Lb,
                                               float2* __restrict__ stats) {
    const int wv = threadIdx.x >> 6;
    const int ln = threadIdx.x & 63;
    const int r0 = blockIdx.x * 4 + wv;       // n*1024 + t
    const int t  = r0 & (T_DIM - 1);
    const ushort* row = Lb + (size_t)r0 * S_DIM;

    float v[2][8];
    #pragma unroll
    for (int it = 0; it < 2; ++it) {
        const int i0 = it * 512 + ln * 8;
        #pragma unroll
        for (int j = 0; j < 8; ++j) v[it][j] = -INFINITY;
        if (i0 <= t) {
            uint4 raw = *(const uint4*)&row[i0];
            v[it][0] = b2f((ushort)(raw.x & 0xffff)); v[it][1] = b2f((ushort)(raw.x >> 16));
            v[it][2] = b2f((ushort)(raw.y & 0xffff)); v[it][3] = b2f((ushort)(raw.y >> 16));
            v[it][4] = b2f((ushort)(raw.z & 0xffff)); v[it][5] = b2f((ushort)(raw.z >> 16));
            v[it][6] = b2f((ushort)(raw.w & 0xffff)); v[it][7] = b2f((ushort)(raw.w >> 16));
            #pragma unroll
            for (int j = 0; j < 8; ++j)
                if (i0 + j > t) v[it][j] = -INFINITY;
        }
    }

    float m = -INFINITY;
    #pragma unroll
    for (int it = 0; it < 2; ++it)
        #pragma unroll
        for (int j = 0; j < 8; ++j) m = fmaxf(m, v[it][j]);
    #pragma unroll
    for (int off = 32; off > 0; off >>= 1) m = fmaxf(m, __shfl_xor(m, off));

    float ssum = 0.0f;
    #pragma unroll
    for (int it = 0; it < 2; ++it)
        #pragma unroll
        for (int j = 0; j < 8; ++j)
            ssum += (v[it][j] > -1e37f) ? __expf(v[it][j] - m) : 0.0f;
    #pragma unroll
    for (int off = 32; off > 0; off >>= 1) ssum += __shfl_xor(ssum, off);

    if (ln == 0) stats[r0] = make_float2(m, 1.0f / ssum);
}

// ---------------------------------------------------------------------------
// proj3: fused cross-head projection, 16t x 32s x 32heads per block.
// LDS 54 KB -> 3 blocks/CU (was 74 KB / 2).
//   Xs: tight [16][32][32] bf16, 16B-chunk XOR swizzle (chunk ^= s&3),
//       t-stride 1040 ush. Staged via register 8x8 transpose: 8 uint4 global
//       loads + 8 ds_write_b128 per thread (was 64 ds_write_u16).
//   Kp: bf16 [16t][32s][16n], s-stride 20 / t-stride 648 ush: uint2 writes
//       minimal-conflict, scalar reads exactly conflict-free.
// SM=true folds softmax (exp(x-m)*inv, causal-zeroed) into staging.
// MFMA operand orientations identical to the round-0-verified proj_mfma.
// ---------------------------------------------------------------------------
template<bool SM>
__global__ __launch_bounds__(256, 3) void proj3(ushort* __restrict__ Lb,
                                                const ushort* __restrict__ Cmat,
                                                const ushort* __restrict__ Kmat,
                                                const float2* __restrict__ stats) {
    const int s0 = blockIdx.x * 32;
    const int t0 = blockIdx.y * 16;
    if (s0 > t0 + 15) return;

    __shared__ __align__(16) ushort Xs[16 * 1040];   // 33280 B
    __shared__ __align__(16) ushort Kpb[16 * 648];   // 20736 B

    const int tid = threadIdx.x;
    const int wv = tid >> 6, ln = tid & 63;
    const int frow = ln & 15, quad = ln >> 4;

    // ---- stage X[t][s][m] <- Lb[m][t0+t][s0+s] via register 8x8 transpose
    {
        const int sc = tid & 3;            // s-chunk (8 s each)
        const int mc = (tid >> 2) & 3;     // m-chunk (8 heads)
        const int tl = tid >> 4;           // t row
        uint4 U[8];
        #pragma unroll
        for (int j = 0; j < 8; ++j) {
            const int n = mc * 8 + j;
            U[j] = *(const uint4*)(Lb + ((size_t)n * T_DIM + t0 + tl) * S_DIM + s0 + sc * 8);
        }
        if (SM) {
            const int tG = t0 + tl;
            #pragma unroll
            for (int j = 0; j < 8; ++j) {
                const float2 ms = stats[(mc * 8 + j) * T_DIM + tG];
                uint* up = (uint*)&U[j];
                #pragma unroll
                for (int w = 0; w < 4; ++w) {
                    const int sg = s0 + sc * 8 + 2 * w;
                    float lo = (sg     <= tG) ? __expf(b2f((ushort)(up[w] & 0xffff)) - ms.x) * ms.y : 0.0f;
                    float hi = (sg + 1 <= tG) ? __expf(b2f((ushort)(up[w] >> 16   )) - ms.x) * ms.y : 0.0f;
                    up[w] = (unsigned)pack_bf16(lo, hi);
                }
            }
        }
        #pragma unroll
        for (int sp = 0; sp < 8; ++sp) {
            const int s = sc * 8 + sp;
            uint4 W;
            W.x = ext16(U[0], sp) | (ext16(U[1], sp) << 16);
            W.y = ext16(U[2], sp) | (ext16(U[3], sp) << 16);
            W.z = ext16(U[4], sp) | (ext16(U[5], sp) << 16);
            W.w = ext16(U[6], sp) | (ext16(U[7], sp) << 16);
            *(uint4*)&Xs[tl * 1040 + s * 32 + ((mc ^ (s & 3)) << 3)] = W;
        }
    }
    __syncthreads();

    #pragma unroll
    for (int mh = 0; mh < 2; ++mh) {
        // ---- K-phase: per s, D[n=16][t=16] = Kmat[s](n,m) x X(m,t,s); K=m=32
        #pragma unroll
        for (int k = 0; k < 8; ++k) {
            const int sl = wv * 8 + k;
            const short8 af = *(const short8*)(Kmat + (size_t)(s0 + sl) * 1024 + (mh * 16 + frow) * 32 + quad * 8);
            const short8 bf = *(const short8*)&Xs[frow * 1040 + sl * 32 + ((quad ^ (sl & 3)) << 3)];
            floatx4 z = {0.f, 0.f, 0.f, 0.f};
            floatx4 d = __builtin_amdgcn_mfma_f32_16x16x32_bf16(af, bf, z, 0, 0, 0);
            // D rows (quad*4+r) = n, cols (frow) = t  ->  Kpb[t][s][n] bf16
            uint2 pk;
            pk.x = (unsigned)pack_bf16(d[0], d[1]);
            pk.y = (unsigned)pack_bf16(d[2], d[3]);
            *(uint2*)&Kpb[frow * 648 + sl * 20 + quad * 4] = pk;
        }
        __syncthreads();

        // ---- C-phase: per t, D[s=16][n=16] = X(s,m,t) x Cmat[t](n,m); add Kp, mask, store
        #pragma unroll
        for (int i = 0; i < 4; ++i) {
            const int tl = wv * 4 + i;
            const int tg = t0 + tl;
            const short8 bf = *(const short8*)(Cmat + (size_t)tg * 1024 + (mh * 16 + frow) * 32 + quad * 8);
            #pragma unroll
            for (int st = 0; st < 2; ++st) {
                const int sA = st * 16 + frow;
                const short8 af = *(const short8*)&Xs[tl * 1040 + sA * 32 + ((quad ^ (sA & 3)) << 3)];
                floatx4 z = {0.f, 0.f, 0.f, 0.f};
                floatx4 d = __builtin_amdgcn_mfma_f32_16x16x32_bf16(af, bf, z, 0, 0, 0);
                // D rows (quad*4+r) = s_local, cols (frow) = n
                float v[4];
                #pragma unroll
                for (int r = 0; r < 4; ++r) {
                    const int sl = st * 16 + quad * 4 + r;
                    float val = d[r] + b2f(Kpb[tl * 648 + sl * 20 + frow]);
                    v[r] = (s0 + sl > tg) ? 0.0f : val;
                }
                uint2 stv;
                stv.x = (unsigned)pack_bf16(v[0], v[1]);
                stv.y = (unsigned)pack_bf16(v[2], v[3]);
                *(uint2*)&Lb[((size_t)(mh * 16 + frow) * T_DIM + tg) * S_DIM + s0 + st * 16 + quad * 4] = stv;
            }
        }
        __syncthreads();   // Kpb reused by next mh
    }
}

// ---------------------------------------------------------------------------
// av3: O = P V via MFMA. (unchanged)
// ---------------------------------------------------------------------------
__global__ __launch_bounds__(256, 4) void av3(const ushort* __restrict__ P,
                                              const ushort* __restrict__ Vt,
                                              float* __restrict__ O) {
    const int tid = threadIdx.x;
    const int wv = tid >> 6, ln = tid & 63;
    const int frow = ln & 15, quad = ln >> 4;
    const int n  = blockIdx.x;
    const int tt = 63 - blockIdx.y;      // big tiles first
    const int t0 = tt * 16;

    __shared__ ushort red[4][16][136];   // 17408 B bf16 partials

    const ushort* Pn  = P  + ((size_t)n * T_DIM + t0) * S_DIM;
    const ushort* Vtn = Vt + (size_t)n * D_HEAD * S_DIM;

    const int nsteps = (t0 + 47) >> 5;   // ceil((t0+16)/32)
    const int nclean = t0 >> 5;          // steps fully below diagonal

    floatx4 acc[8] = {};
    for (int sb = wv; sb < nsteps; sb += 4) {
        short8 a = *(const short8*)(Pn + (size_t)frow * S_DIM + sb * 32 + quad * 8);
        if (sb >= nclean) {
            const int tg  = t0 + frow;
            const int sg0 = sb * 32 + quad * 8;
            #pragma unroll
            for (int j = 0; j < 8; ++j)
                if (sg0 + j > tg) a[j] = 0;
        }
        #pragma unroll
        for (int dc = 0; dc < 8; ++dc) {
            const short8 b = *(const short8*)(Vtn + (size_t)(dc * 16 + frow) * S_DIM + sb * 32 + quad * 8);
            acc[dc] = __builtin_amdgcn_mfma_f32_16x16x32_bf16(a, b, acc[dc], 0, 0, 0);
        }
    }

    #pragma unroll
    for (int dc = 0; dc < 8; ++dc)
        #pragma unroll
        for (int r = 0; r < 4; ++r)
            red[wv][quad * 4 + r][dc * 16 + frow] = f2b(acc[dc][r]);
    __syncthreads();

    #pragma unroll
    for (int it = 0; it < 2; ++it) {
        int idx = tid + it * 256;
        int d4 = idx & 31, tr = idx >> 5;
        float4 v;
        v.x = b2f(red[0][tr][d4 * 4 + 0]) + b2f(red[1][tr][d4 * 4 + 0]) + b2f(red[2][tr][d4 * 4 + 0]) + b2f(red[3][tr][d4 * 4 + 0]);
        v.y = b2f(red[0][tr][d4 * 4 + 1]) + b2f(red[1][tr][d4 * 4 + 1]) + b2f(red[2][tr][d4 * 4 + 1]) + b2f(red[3][tr][d4 * 4 + 1]);
        v.z = b2f(red[0][tr][d4 * 4 + 2]) + b2f(red[1][tr][d4 * 4 + 2]) + b2f(red[2][tr][d4 * 4 + 2]) + b2f(red[3][tr][d4 * 4 + 2]);
        v.w = b2f(red[0][tr][d4 * 4 + 3]) + b2f(red[1][tr][d4 * 4 + 3]) + b2f(red[2][tr][d4 * 4 + 3]) + b2f(red[3][tr][d4 * 4 + 3]);
        *(float4*)&O[((size_t)n * T_DIM + t0 + tr) * D_HEAD + d4 * 4] = v;
    }
}

// ---------------------------------------------------------------------------
extern "C" void kernel_launch(void* const* d_in, const int* in_sizes, int n_in,
                              void* d_out, int out_size, void* d_ws, size_t ws_size,
                              hipStream_t stream) {
    const float* Q    = (const float*)d_in[0];
    const float* K    = (const float*)d_in[1];
    const float* V    = (const float*)d_in[2];
    const float* sw_pre  = (const float*)d_in[4];
    const float* qw1_pre = (const float*)d_in[5];
    const float* qw2_pre = (const float*)d_in[6];
    const float* kw1_pre = (const float*)d_in[7];
    const float* kw2_pre = (const float*)d_in[8];
    const float* qdd_pre = (const float*)d_in[9];
    const float* kdd_pre = (const float*)d_in[10];
    const float* sw_post  = (const float*)d_in[11];
    const float* qw1_post = (const float*)d_in[12];
    const float* qw2_post = (const float*)d_in[13];
    const float* kw1_post = (const float*)d_in[14];
    const float* kw2_post = (const float*)d_in[15];
    const float* qdd_post = (const float*)d_in[16];
    const float* kdd_post = (const float*)d_in[17];

    // ws: L bf16 [32][1024][1024] = 64 MB, then Vt bf16 [32][128][1024] = 8 MB
    ushort* Lb = (ushort*)d_ws;
    ushort* Vt = (ushort*)((char*)d_ws + (size_t)N_HEADS * T_DIM * S_DIM * 2);
    float*  O  = (float*)d_out;

    // d_out scratch (16 MB): mats in first 8 MB, softmax stats after.
    // Both fully consumed before av3 overwrites d_out.
    ushort* mats  = (ushort*)d_out;
    ushort* Cpre  = mats + 0 * 1024 * 1024;
    ushort* Kpre  = mats + 1 * 1024 * 1024;
    ushort* Cpost = mats + 2 * 1024 * 1024;
    ushort* Kpost = mats + 3 * 1024 * 1024;
    float2* stats = (float2*)((char*)d_out + (size_t)8 * 1024 * 1024);

    mat4_kernel<<<dim3(1024, 4), 256, 0, stream>>>(
        sw_pre, qw1_pre, qw2_pre, qdd_pre, kw1_pre, kw2_pre, kdd_pre,
        sw_post, qw1_post, qw2_post, qdd_post, kw1_post, kw2_post, kdd_post, mats);
    vt_kernel<<<dim3(16, 32), 256, 0, stream>>>(V, Vt);

    qk_mfma<<<dim3(16, 16, 32), 256, 0, stream>>>(Q, K, Lb);
    proj3<false><<<dim3(32, 64), 256, 0, stream>>>(Lb, Cpre, Kpre, nullptr);
    rowstat<<<dim3(8192), 256, 0, stream>>>(Lb, stats);
    proj3<true><<<dim3(32, 64), 256, 0, stream>>>(Lb, Cpost, Kpost, stats);
    av3<<<dim3(32, 64), 256, 0, stream>>>(Lb, Vt, O);
}

// Round 4
// 298.233 us; speedup vs baseline: 1.0186x; 1.0186x over previous
//
#include <hip/hip_runtime.h>
#include <hip/hip_bf16.h>
#include <cstdint>
#include <cstddef>

#define T_DIM 1024
#define S_DIM 1024
#define N_HEADS 32
#define D_HEAD 128

typedef __attribute__((ext_vector_type(8))) short short8;
typedef __attribute__((ext_vector_type(4))) float floatx4;

__device__ inline int pack_bf16(float a, float b) {
    __hip_bfloat162 h = __float22bfloat162_rn(make_float2(a, b));
    int r; __builtin_memcpy(&r, &h, 4); return r;
}
__device__ inline ushort f2b(float x) {
    __hip_bfloat16 h = __float2bfloat16(x);
    ushort u; __builtin_memcpy(&u, &h, 2); return u;
}
__device__ inline float b2f(ushort u) {
    unsigned int v = ((unsigned int)u) << 16;
    float f; __builtin_memcpy(&f, &v, 4); return f;
}

// ---------------------------------------------------------------------------
// Vt[n][d][s] bf16 <- V[n][s][d] fp32.  64s x 128d tile per block. (unchanged)
// ---------------------------------------------------------------------------
__global__ __launch_bounds__(256) void vt_kernel(const float* __restrict__ V,
                                                 ushort* __restrict__ Vt) {
    const int s0 = blockIdx.x * 64;
    const int n  = blockIdx.y;
    __shared__ float lds[128 * 65];

    const int tid = threadIdx.x;
    const float* Vn = V + ((size_t)n * S_DIM + s0) * D_HEAD;

    #pragma unroll
    for (int it = 0; it < 8; ++it) {
        int idx = tid + it * 256;
        int d4 = idx & 31, s = idx >> 5;
        float4 v = *(const float4*)(Vn + (size_t)s * D_HEAD + d4 * 4);
        lds[(d4 * 4 + 0) * 65 + s] = v.x;
        lds[(d4 * 4 + 1) * 65 + s] = v.y;
        lds[(d4 * 4 + 2) * 65 + s] = v.z;
        lds[(d4 * 4 + 3) * 65 + s] = v.w;
    }
    __syncthreads();

    ushort* Vtn = Vt + (size_t)n * D_HEAD * S_DIM;
    #pragma unroll
    for (int it = 0; it < 4; ++it) {
        int idx = tid + it * 256;
        int sg = idx & 7, d = idx >> 3;
        const float* src = &lds[d * 65 + sg * 8];
        int4 o;
        o.x = pack_bf16(src[0], src[1]);
        o.y = pack_bf16(src[2], src[3]);
        o.z = pack_bf16(src[4], src[5]);
        o.w = pack_bf16(src[6], src[7]);
        *(int4*)&Vtn[(size_t)d * S_DIM + s0 + sg * 8] = o;
    }
}

// ---------------------------------------------------------------------------
// K1: logits (bf16) via MFMA, 64x64 causal tiles. (unchanged)
// ---------------------------------------------------------------------------
__global__ __launch_bounds__(256, 2) void qk_mfma(const float* __restrict__ Q,
                                                  const float* __restrict__ K,
                                                  ushort* __restrict__ Lb) {
    const int st = blockIdx.x;
    const int tt = blockIdx.y;
    const int n  = blockIdx.z;
    if (st > tt) return;

    __shared__ int Qt[64 * 64];
    __shared__ int Kt[64 * 64];

    const int tid = threadIdx.x;
    const int wv = tid >> 6, ln = tid & 63;
    const int frow = ln & 15, quad = ln >> 4;

    const float* Qn = Q + ((size_t)n * T_DIM + (size_t)tt * 64) * D_HEAD;
    const float* Kn = K + ((size_t)n * S_DIM + (size_t)st * 64) * D_HEAD;

    #pragma unroll
    for (int rep = 0; rep < 8; ++rep) {
        int idx = tid + rep * 256;
        int row = idx >> 5;
        int c4  = (idx & 31) * 4;
        int p   = c4 >> 1;
        int kb  = p >> 4, w = p & 15;
        int swz = 4 * (row & 3);
        float4 q = *(const float4*)(Qn + (size_t)row * D_HEAD + c4);
        int2 qv; qv.x = pack_bf16(q.x, q.y); qv.y = pack_bf16(q.z, q.w);
        *(int2*)&Qt[row * 64 + kb * 16 + (w ^ swz)] = qv;
        float4 k = *(const float4*)(Kn + (size_t)row * D_HEAD + c4);
        int2 kv; kv.x = pack_bf16(k.x, k.y); kv.y = pack_bf16(k.z, k.w);
        *(int2*)&Kt[row * 64 + kb * 16 + (w ^ swz)] = kv;
    }
    __syncthreads();

    const int swz = 4 * (frow & 3);
    floatx4 acc[4] = {};
    #pragma unroll
    for (int kb = 0; kb < 4; ++kb) {
        const short8 af = *(const short8*)&Qt[(wv * 16 + frow) * 64 + kb * 16 + ((quad * 4) ^ swz)];
        #pragma unroll
        for (int si = 0; si < 4; ++si) {
            const short8 bf = *(const short8*)&Kt[(si * 16 + frow) * 64 + kb * 16 + ((quad * 4) ^ swz)];
            acc[si] = __builtin_amdgcn_mfma_f32_16x16x32_bf16(af, bf, acc[si], 0, 0, 0);
        }
    }
    __syncthreads();                    // Qt dead -> reuse as output tile

    ushort* Ot = (ushort*)Qt;           // [64][72] bf16
    #pragma unroll
    for (int si = 0; si < 4; ++si)
        #pragma unroll
        for (int r = 0; r < 4; ++r)
            Ot[(wv * 16 + quad * 4 + r) * 72 + si * 16 + frow] = f2b(acc[si][r]);
    __syncthreads();

    #pragma unroll
    for (int it = 0; it < 2; ++it) {
        int idx = tid + it * 256;
        int row = idx >> 3, col = idx & 7;
        int4 v = *(const int4*)&Ot[row * 72 + col * 8];
        *(int4*)&Lb[((size_t)n * T_DIM + tt * 64 + row) * S_DIM + st * 64 + col * 8] = v;
    }
}

// ---------------------------------------------------------------------------
// Precompute all four 32x32 mixing-matrix families in one launch. (unchanged)
// ---------------------------------------------------------------------------
__global__ __launch_bounds__(256) void mat4_kernel(
        const float* __restrict__ sw_pre,  const float* __restrict__ qw1_pre,
        const float* __restrict__ qw2_pre, const float* __restrict__ qdd_pre,
        const float* __restrict__ kw1_pre, const float* __restrict__ kw2_pre,
        const float* __restrict__ kdd_pre,
        const float* __restrict__ sw_post,  const float* __restrict__ qw1_post,
        const float* __restrict__ qw2_post, const float* __restrict__ qdd_post,
        const float* __restrict__ kw1_post, const float* __restrict__ kw2_post,
        const float* __restrict__ kdd_post,
        ushort* __restrict__ mats) {
    const float *sw, *w1, *w2, *dd;
    float idadd;
    switch (blockIdx.y) {
        case 0:  sw = sw_pre;  w1 = qw1_pre;  w2 = qw2_pre;  dd = qdd_pre;  idadd = 1.0f; break;
        case 1:  sw = nullptr; w1 = kw1_pre;  w2 = kw2_pre;  dd = kdd_pre;  idadd = 0.0f; break;
        case 2:  sw = sw_post; w1 = qw1_post; w2 = qw2_post; dd = qdd_post; idadd = 1.0f; break;
        default: sw = nullptr; w1 = kw1_post; w2 = kw2_post; dd = kdd_post; idadd = 0.0f; break;
    }
    ushort* out = mats + (size_t)blockIdx.y * 1024 * 1024;

    const int t = blockIdx.x;
    const int tid = threadIdx.x;
    const int m = tid >> 3;
    const int n0 = (tid & 7) * 4;

    const float w2m0 = w2[t * 64 + m];
    const float w2m1 = w2[t * 64 + 32 + m];
    const float ddm  = dd[t * 32 + m];

    float v[4];
    #pragma unroll
    for (int j = 0; j < 4; ++j) {
        int n = n0 + j;
        float r = w1[t * 64 + n] * w2m0 + w1[t * 64 + 32 + n] * w2m1;
        if (sw) r += sw[n * 32 + m];
        if (n == m) r += idadd + ddm;
        v[j] = r;
    }
    int p0 = pack_bf16(v[0], v[1]);
    int p1 = pack_bf16(v[2], v[3]);
    int2 st = make_int2(p0, p1);
    *(int2*)&out[(size_t)t * 1024 + m * 32 + n0] = st;
}

// ---------------------------------------------------------------------------
// rowstat: per-(n,t) softmax stats. One wave per row, 4 rows/block. (unchanged)
// ---------------------------------------------------------------------------
__global__ __launch_bounds__(256) void rowstat(const ushort* __restrict__ Lb,
                                               float2* __restrict__ stats) {
    const int wv = threadIdx.x >> 6;
    const int ln = threadIdx.x & 63;
    const int r0 = blockIdx.x * 4 + wv;       // n*1024 + t
    const int t  = r0 & (T_DIM - 1);
    const ushort* row = Lb + (size_t)r0 * S_DIM;

    float v[2][8];
    #pragma unroll
    for (int it = 0; it < 2; ++it) {
        const int i0 = it * 512 + ln * 8;
        #pragma unroll
        for (int j = 0; j < 8; ++j) v[it][j] = -INFINITY;
        if (i0 <= t) {
            uint4 raw = *(const uint4*)&row[i0];
            v[it][0] = b2f((ushort)(raw.x & 0xffff)); v[it][1] = b2f((ushort)(raw.x >> 16));
            v[it][2] = b2f((ushort)(raw.y & 0xffff)); v[it][3] = b2f((ushort)(raw.y >> 16));
            v[it][4] = b2f((ushort)(raw.z & 0xffff)); v[it][5] = b2f((ushort)(raw.z >> 16));
            v[it][6] = b2f((ushort)(raw.w & 0xffff)); v[it][7] = b2f((ushort)(raw.w >> 16));
            #pragma unroll
            for (int j = 0; j < 8; ++j)
                if (i0 + j > t) v[it][j] = -INFINITY;
        }
    }

    float m = -INFINITY;
    #pragma unroll
    for (int it = 0; it < 2; ++it)
        #pragma unroll
        for (int j = 0; j < 8; ++j) m = fmaxf(m, v[it][j]);
    #pragma unroll
    for (int off = 32; off > 0; off >>= 1) m = fmaxf(m, __shfl_xor(m, off));

    float ssum = 0.0f;
    #pragma unroll
    for (int it = 0; it < 2; ++it)
        #pragma unroll
        for (int j = 0; j < 8; ++j)
            ssum += (v[it][j] > -1e37f) ? __expf(v[it][j] - m) : 0.0f;
    #pragma unroll
    for (int off = 32; off > 0; off >>= 1) ssum += __shfl_xor(ssum, off);

    if (ln == 0) stats[r0] = make_float2(m, 1.0f / ssum);
}

// ---------------------------------------------------------------------------
// proj4: fused cross-head projection, 16t x 16s x all-32-heads per block.
// Exact round-2 (44 us verified) phase/staging code, s-tile halved 32 -> 16:
//   - active blocks 1056 -> 2080 (the work-parallelism axis that binds)
//   - LDS 37.4 KB -> 4 blocks/CU resident (was 74 KB / 2)
//   - all LDS strides keep round-2 bank residues (648: 324 dw = 4 mod 32,
//     matching 1288's 644 = 4 mod 32; Kp 260 = 4 mod 32 matching 516)
// SM=true folds softmax (exp(x-m)*inv, causal-zeroed) into staging.
// ---------------------------------------------------------------------------
template<bool SM>
__global__ __launch_bounds__(256, 4) void proj4(ushort* __restrict__ Lb,
                                                const ushort* __restrict__ Cmat,
                                                const ushort* __restrict__ Kmat,
                                                const float2* __restrict__ stats) {
    const int s0 = blockIdx.x * 16;
    const int t0 = blockIdx.y * 16;
    if (s0 > t0 + 15) return;            // bx > by: fully masked tile

    __shared__ __align__(16) ushort Xs[16 * 648];   // 20736 B  [t][s:40][m]
    __shared__ __align__(16) float  Kp[16 * 260];   // 16640 B  [t][s:16][n]

    const int tid = threadIdx.x;
    const int wv = tid >> 6, ln = tid & 63;
    const int frow = ln & 15, quad = ln >> 4;

    // ---- stage X[t][s][m] <- Lb[m][t0+t][s0+s] (transpose head -> contiguous)
    #pragma unroll
    for (int it = 0; it < 4; ++it) {
        int slot = tid + it * 256;           // 1024 slots = 512 rows x 2 chunks
        int c    = slot & 1;                 // 16 B chunk -> 8 s values
        int row  = slot >> 1;                // n*16 + t
        int nn   = row >> 4, tl = row & 15;
        uint4 ld = *(const uint4*)(Lb + ((size_t)nn * T_DIM + t0 + tl) * S_DIM + s0 + c * 8);
        ushort u[8];
        u[0] = (ushort)(ld.x & 0xffff);  u[1] = (ushort)(ld.x >> 16);
        u[2] = (ushort)(ld.y & 0xffff);  u[3] = (ushort)(ld.y >> 16);
        u[4] = (ushort)(ld.z & 0xffff);  u[5] = (ushort)(ld.z >> 16);
        u[6] = (ushort)(ld.w & 0xffff);  u[7] = (ushort)(ld.w >> 16);
        if (SM) {
            const float2 ms = stats[nn * T_DIM + t0 + tl];
            const int tG = t0 + tl, sbase = s0 + c * 8;
            #pragma unroll
            for (int j = 0; j < 8; ++j) {
                float x = (sbase + j <= tG) ? __expf(b2f(u[j]) - ms.x) * ms.y : 0.0f;
                u[j] = f2b(x);
            }
        }
        ushort* xp = &Xs[tl * 648 + (c * 8) * 40 + nn];
        #pragma unroll
        for (int j = 0; j < 8; ++j) xp[j * 40] = u[j];
    }
    __syncthreads();

    #pragma unroll
    for (int mh = 0; mh < 2; ++mh) {
        // ---- K-phase: per s, D[n=16][t=16] = Kmat[s](n,m) x X(m,t,s); K=m=32
        #pragma unroll
        for (int k = 0; k < 4; ++k) {
            const int sl = wv * 4 + k;
            const short8 af = *(const short8*)(Kmat + (size_t)(s0 + sl) * 1024 + (mh * 16 + frow) * 32 + quad * 8);
            const short8 bf = *(const short8*)&Xs[frow * 648 + sl * 40 + quad * 8];
            floatx4 z = {0.f, 0.f, 0.f, 0.f};
            floatx4 d = __builtin_amdgcn_mfma_f32_16x16x32_bf16(af, bf, z, 0, 0, 0);
            // D rows (quad*4+r) = n, cols (frow) = t  ->  Kp[t][s][n]
            *(floatx4*)&Kp[frow * 260 + sl * 16 + quad * 4] = d;
        }
        __syncthreads();

        // ---- C-phase: per t, D[s=16][n=16] = X(s,m,t) x Cmat[t](n,m); add Kp, mask, store
        #pragma unroll
        for (int i = 0; i < 4; ++i) {
            const int tl = wv * 4 + i;
            const int tg = t0 + tl;
            const short8 bf = *(const short8*)(Cmat + (size_t)tg * 1024 + (mh * 16 + frow) * 32 + quad * 8);
            const short8 af = *(const short8*)&Xs[tl * 648 + frow * 40 + quad * 8];
            floatx4 z = {0.f, 0.f, 0.f, 0.f};
            floatx4 d = __builtin_amdgcn_mfma_f32_16x16x32_bf16(af, bf, z, 0, 0, 0);
            // D rows (quad*4+r) = s_local, cols (frow) = n
            float v[4];
            #pragma unroll
            for (int r = 0; r < 4; ++r) {
                const int sl = quad * 4 + r;
                float val = d[r] + Kp[tl * 260 + sl * 16 + frow];
                v[r] = (s0 + sl > tg) ? 0.0f : val;
            }
            uint2 stv;
            stv.x = (unsigned)pack_bf16(v[0], v[1]);
            stv.y = (unsigned)pack_bf16(v[2], v[3]);
            *(uint2*)&Lb[((size_t)(mh * 16 + frow) * T_DIM + tg) * S_DIM + s0 + quad * 4] = stv;
        }
        __syncthreads();   // Kp reused by next mh
    }
}

// ---------------------------------------------------------------------------
// av3: O = P V via MFMA. (unchanged)
// ---------------------------------------------------------------------------
__global__ __launch_bounds__(256, 4) void av3(const ushort* __restrict__ P,
                                              const ushort* __restrict__ Vt,
                                              float* __restrict__ O) {
    const int tid = threadIdx.x;
    const int wv = tid >> 6, ln = tid & 63;
    const int frow = ln & 15, quad = ln >> 4;
    const int n  = blockIdx.x;
    const int tt = 63 - blockIdx.y;      // big tiles first
    const int t0 = tt * 16;

    __shared__ ushort red[4][16][136];   // 17408 B bf16 partials

    const ushort* Pn  = P  + ((size_t)n * T_DIM + t0) * S_DIM;
    const ushort* Vtn = Vt + (size_t)n * D_HEAD * S_DIM;

    const int nsteps = (t0 + 47) >> 5;   // ceil((t0+16)/32)
    const int nclean = t0 >> 5;          // steps fully below diagonal

    floatx4 acc[8] = {};
    for (int sb = wv; sb < nsteps; sb += 4) {
        short8 a = *(const short8*)(Pn + (size_t)frow * S_DIM + sb * 32 + quad * 8);
        if (sb >= nclean) {
            const int tg  = t0 + frow;
            const int sg0 = sb * 32 + quad * 8;
            #pragma unroll
            for (int j = 0; j < 8; ++j)
                if (sg0 + j > tg) a[j] = 0;
        }
        #pragma unroll
        for (int dc = 0; dc < 8; ++dc) {
            const short8 b = *(const short8*)(Vtn + (size_t)(dc * 16 + frow) * S_DIM + sb * 32 + quad * 8);
            acc[dc] = __builtin_amdgcn_mfma_f32_16x16x32_bf16(a, b, acc[dc], 0, 0, 0);
        }
    }

    #pragma unroll
    for (int dc = 0; dc < 8; ++dc)
        #pragma unroll
        for (int r = 0; r < 4; ++r)
            red[wv][quad * 4 + r][dc * 16 + frow] = f2b(acc[dc][r]);
    __syncthreads();

    #pragma unroll
    for (int it = 0; it < 2; ++it) {
        int idx = tid + it * 256;
        int d4 = idx & 31, tr = idx >> 5;
        float4 v;
        v.x = b2f(red[0][tr][d4 * 4 + 0]) + b2f(red[1][tr][d4 * 4 + 0]) + b2f(red[2][tr][d4 * 4 + 0]) + b2f(red[3][tr][d4 * 4 + 0]);
        v.y = b2f(red[0][tr][d4 * 4 + 1]) + b2f(red[1][tr][d4 * 4 + 1]) + b2f(red[2][tr][d4 * 4 + 1]) + b2f(red[3][tr][d4 * 4 + 1]);
        v.z = b2f(red[0][tr][d4 * 4 + 2]) + b2f(red[1][tr][d4 * 4 + 2]) + b2f(red[2][tr][d4 * 4 + 2]) + b2f(red[3][tr][d4 * 4 + 2]);
        v.w = b2f(red[0][tr][d4 * 4 + 3]) + b2f(red[1][tr][d4 * 4 + 3]) + b2f(red[2][tr][d4 * 4 + 3]) + b2f(red[3][tr][d4 * 4 + 3]);
        *(float4*)&O[((size_t)n * T_DIM + t0 + tr) * D_HEAD + d4 * 4] = v;
    }
}

// ---------------------------------------------------------------------------
extern "C" void kernel_launch(void* const* d_in, const int* in_sizes, int n_in,
                              void* d_out, int out_size, void* d_ws, size_t ws_size,
                              hipStream_t stream) {
    const float* Q    = (const float*)d_in[0];
    const float* K    = (const float*)d_in[1];
    const float* V    = (const float*)d_in[2];
    const float* sw_pre  = (const float*)d_in[4];
    const float* qw1_pre = (const float*)d_in[5];
    const float* qw2_pre = (const float*)d_in[6];
    const float* kw1_pre = (const float*)d_in[7];
    const float* kw2_pre = (const float*)d_in[8];
    const float* qdd_pre = (const float*)d_in[9];
    const float* kdd_pre = (const float*)d_in[10];
    const float* sw_post  = (const float*)d_in[11];
    const float* qw1_post = (const float*)d_in[12];
    const float* qw2_post = (const float*)d_in[13];
    const float* kw1_post = (const float*)d_in[14];
    const float* kw2_post = (const float*)d_in[15];
    const float* qdd_post = (const float*)d_in[16];
    const float* kdd_post = (const float*)d_in[17];

    // ws: L bf16 [32][1024][1024] = 64 MB, then Vt bf16 [32][128][1024] = 8 MB
    ushort* Lb = (ushort*)d_ws;
    ushort* Vt = (ushort*)((char*)d_ws + (size_t)N_HEADS * T_DIM * S_DIM * 2);
    float*  O  = (float*)d_out;

    // d_out scratch (16 MB): mats in first 8 MB, softmax stats after.
    // Both fully consumed before av3 overwrites d_out.
    ushort* mats  = (ushort*)d_out;
    ushort* Cpre  = mats + 0 * 1024 * 1024;
    ushort* Kpre  = mats + 1 * 1024 * 1024;
    ushort* Cpost = mats + 2 * 1024 * 1024;
    ushort* Kpost = mats + 3 * 1024 * 1024;
    float2* stats = (float2*)((char*)d_out + (size_t)8 * 1024 * 1024);

    mat4_kernel<<<dim3(1024, 4), 256, 0, stream>>>(
        sw_pre, qw1_pre, qw2_pre, qdd_pre, kw1_pre, kw2_pre, kdd_pre,
        sw_post, qw1_post, qw2_post, qdd_post, kw1_post, kw2_post, kdd_post, mats);
    vt_kernel<<<dim3(16, 32), 256, 0, stream>>>(V, Vt);

    qk_mfma<<<dim3(16, 16, 32), 256, 0, stream>>>(Q, K, Lb);
    proj4<false><<<dim3(64, 64), 256, 0, stream>>>(Lb, Cpre, Kpre, nullptr);
    rowstat<<<dim3(8192), 256, 0, stream>>>(Lb, stats);
    proj4<true><<<dim3(64, 64), 256, 0, stream>>>(Lb, Cpost, Kpost, stats);
    av3<<<dim3(32, 64), 256, 0, stream>>>(Lb, Vt, O);
}

// Round 5
// 262.625 us; speedup vs baseline: 1.1567x; 1.1356x over previous
//
#include <hip/hip_runtime.h>
#include <hip/hip_bf16.h>
#include <cstdint>
#include <cstddef>

#define T_DIM 1024
#define S_DIM 1024
#define N_HEADS 32
#define D_HEAD 128

typedef __attribute__((ext_vector_type(8))) short short8;
typedef __attribute__((ext_vector_type(4))) float floatx4;

__device__ inline int pack_bf16(float a, float b) {
    __hip_bfloat162 h = __float22bfloat162_rn(make_float2(a, b));
    int r; __builtin_memcpy(&r, &h, 4); return r;
}
__device__ inline ushort f2b(float x) {
    __hip_bfloat16 h = __float2bfloat16(x);
    ushort u; __builtin_memcpy(&u, &h, 2); return u;
}
__device__ inline float b2f(ushort u) {
    unsigned int v = ((unsigned int)u) << 16;
    float f; __builtin_memcpy(&f, &v, 4); return f;
}

// ---------------------------------------------------------------------------
// Vt[n][d][s] bf16 <- V[n][s][d] fp32.  64s x 128d tile per block. (unchanged)
// ---------------------------------------------------------------------------
__global__ __launch_bounds__(256) void vt_kernel(const float* __restrict__ V,
                                                 ushort* __restrict__ Vt) {
    const int s0 = blockIdx.x * 64;
    const int n  = blockIdx.y;
    __shared__ float lds[128 * 65];

    const int tid = threadIdx.x;
    const float* Vn = V + ((size_t)n * S_DIM + s0) * D_HEAD;

    #pragma unroll
    for (int it = 0; it < 8; ++it) {
        int idx = tid + it * 256;
        int d4 = idx & 31, s = idx >> 5;
        float4 v = *(const float4*)(Vn + (size_t)s * D_HEAD + d4 * 4);
        lds[(d4 * 4 + 0) * 65 + s] = v.x;
        lds[(d4 * 4 + 1) * 65 + s] = v.y;
        lds[(d4 * 4 + 2) * 65 + s] = v.z;
        lds[(d4 * 4 + 3) * 65 + s] = v.w;
    }
    __syncthreads();

    ushort* Vtn = Vt + (size_t)n * D_HEAD * S_DIM;
    #pragma unroll
    for (int it = 0; it < 4; ++it) {
        int idx = tid + it * 256;
        int sg = idx & 7, d = idx >> 3;
        const float* src = &lds[d * 65 + sg * 8];
        int4 o;
        o.x = pack_bf16(src[0], src[1]);
        o.y = pack_bf16(src[2], src[3]);
        o.z = pack_bf16(src[4], src[5]);
        o.w = pack_bf16(src[6], src[7]);
        *(int4*)&Vtn[(size_t)d * S_DIM + s0 + sg * 8] = o;
    }
}

// ---------------------------------------------------------------------------
// K1: logits (bf16) via MFMA, 64x64 causal tiles. Ot epilogue staging now
// bank-swizzled: logical column c stored at c ^ (16*((row>>3)&1)) -> u16
// write conflicts drop 4-way -> 2-way (free); reads apply same XOR (bit 4
// only, so 16 B alignment and contiguity preserved).
// ---------------------------------------------------------------------------
__global__ __launch_bounds__(256, 2) void qk_mfma(const float* __restrict__ Q,
                                                  const float* __restrict__ K,
                                                  ushort* __restrict__ Lb) {
    const int st = blockIdx.x;
    const int tt = blockIdx.y;
    const int n  = blockIdx.z;
    if (st > tt) return;

    __shared__ int Qt[64 * 64];
    __shared__ int Kt[64 * 64];

    const int tid = threadIdx.x;
    const int wv = tid >> 6, ln = tid & 63;
    const int frow = ln & 15, quad = ln >> 4;

    const float* Qn = Q + ((size_t)n * T_DIM + (size_t)tt * 64) * D_HEAD;
    const float* Kn = K + ((size_t)n * S_DIM + (size_t)st * 64) * D_HEAD;

    #pragma unroll
    for (int rep = 0; rep < 8; ++rep) {
        int idx = tid + rep * 256;
        int row = idx >> 5;
        int c4  = (idx & 31) * 4;
        int p   = c4 >> 1;
        int kb  = p >> 4, w = p & 15;
        int swz = 4 * (row & 3);
        float4 q = *(const float4*)(Qn + (size_t)row * D_HEAD + c4);
        int2 qv; qv.x = pack_bf16(q.x, q.y); qv.y = pack_bf16(q.z, q.w);
        *(int2*)&Qt[row * 64 + kb * 16 + (w ^ swz)] = qv;
        float4 k = *(const float4*)(Kn + (size_t)row * D_HEAD + c4);
        int2 kv; kv.x = pack_bf16(k.x, k.y); kv.y = pack_bf16(k.z, k.w);
        *(int2*)&Kt[row * 64 + kb * 16 + (w ^ swz)] = kv;
    }
    __syncthreads();

    const int swz = 4 * (frow & 3);
    floatx4 acc[4] = {};
    #pragma unroll
    for (int kb = 0; kb < 4; ++kb) {
        const short8 af = *(const short8*)&Qt[(wv * 16 + frow) * 64 + kb * 16 + ((quad * 4) ^ swz)];
        #pragma unroll
        for (int si = 0; si < 4; ++si) {
            const short8 bf = *(const short8*)&Kt[(si * 16 + frow) * 64 + kb * 16 + ((quad * 4) ^ swz)];
            acc[si] = __builtin_amdgcn_mfma_f32_16x16x32_bf16(af, bf, acc[si], 0, 0, 0);
        }
    }
    __syncthreads();                    // Qt dead -> reuse as output tile

    ushort* Ot = (ushort*)Qt;           // [64][72] bf16, column-swizzled
    #pragma unroll
    for (int si = 0; si < 4; ++si)
        #pragma unroll
        for (int r = 0; r < 4; ++r)
            Ot[(wv * 16 + quad * 4 + r) * 72 + ((si ^ (quad >> 1)) * 16) + frow] = f2b(acc[si][r]);
    __syncthreads();

    #pragma unroll
    for (int it = 0; it < 2; ++it) {
        int idx = tid + it * 256;
        int row = idx >> 3, col = idx & 7;
        int4 v = *(const int4*)&Ot[row * 72 + ((col * 8) ^ (((row >> 3) & 1) * 16))];
        *(int4*)&Lb[((size_t)n * T_DIM + tt * 64 + row) * S_DIM + st * 64 + col * 8] = v;
    }
}

// ---------------------------------------------------------------------------
// Precompute all four 32x32 mixing-matrix families in one launch. (unchanged)
// ---------------------------------------------------------------------------
__global__ __launch_bounds__(256) void mat4_kernel(
        const float* __restrict__ sw_pre,  const float* __restrict__ qw1_pre,
        const float* __restrict__ qw2_pre, const float* __restrict__ qdd_pre,
        const float* __restrict__ kw1_pre, const float* __restrict__ kw2_pre,
        const float* __restrict__ kdd_pre,
        const float* __restrict__ sw_post,  const float* __restrict__ qw1_post,
        const float* __restrict__ qw2_post, const float* __restrict__ qdd_post,
        const float* __restrict__ kw1_post, const float* __restrict__ kw2_post,
        const float* __restrict__ kdd_post,
        ushort* __restrict__ mats) {
    const float *sw, *w1, *w2, *dd;
    float idadd;
    switch (blockIdx.y) {
        case 0:  sw = sw_pre;  w1 = qw1_pre;  w2 = qw2_pre;  dd = qdd_pre;  idadd = 1.0f; break;
        case 1:  sw = nullptr; w1 = kw1_pre;  w2 = kw2_pre;  dd = kdd_pre;  idadd = 0.0f; break;
        case 2:  sw = sw_post; w1 = qw1_post; w2 = qw2_post; dd = qdd_post; idadd = 1.0f; break;
        default: sw = nullptr; w1 = kw1_post; w2 = kw2_post; dd = kdd_post; idadd = 0.0f; break;
    }
    ushort* out = mats + (size_t)blockIdx.y * 1024 * 1024;

    const int t = blockIdx.x;
    const int tid = threadIdx.x;
    const int m = tid >> 3;
    const int n0 = (tid & 7) * 4;

    const float w2m0 = w2[t * 64 + m];
    const float w2m1 = w2[t * 64 + 32 + m];
    const float ddm  = dd[t * 32 + m];

    float v[4];
    #pragma unroll
    for (int j = 0; j < 4; ++j) {
        int n = n0 + j;
        float r = w1[t * 64 + n] * w2m0 + w1[t * 64 + 32 + n] * w2m1;
        if (sw) r += sw[n * 32 + m];
        if (n == m) r += idadd + ddm;
        v[j] = r;
    }
    int p0 = pack_bf16(v[0], v[1]);
    int p1 = pack_bf16(v[2], v[3]);
    int2 st = make_int2(p0, p1);
    *(int2*)&out[(size_t)t * 1024 + m * 32 + n0] = st;
}

// ---------------------------------------------------------------------------
// rowstat: per-(n,t) softmax stats. One wave per row, 4 rows/block. (unchanged)
// ---------------------------------------------------------------------------
__global__ __launch_bounds__(256) void rowstat(const ushort* __restrict__ Lb,
                                               float2* __restrict__ stats) {
    const int wv = threadIdx.x >> 6;
    const int ln = threadIdx.x & 63;
    const int r0 = blockIdx.x * 4 + wv;       // n*1024 + t
    const int t  = r0 & (T_DIM - 1);
    const ushort* row = Lb + (size_t)r0 * S_DIM;

    float v[2][8];
    #pragma unroll
    for (int it = 0; it < 2; ++it) {
        const int i0 = it * 512 + ln * 8;
        #pragma unroll
        for (int j = 0; j < 8; ++j) v[it][j] = -INFINITY;
        if (i0 <= t) {
            uint4 raw = *(const uint4*)&row[i0];
            v[it][0] = b2f((ushort)(raw.x & 0xffff)); v[it][1] = b2f((ushort)(raw.x >> 16));
            v[it][2] = b2f((ushort)(raw.y & 0xffff)); v[it][3] = b2f((ushort)(raw.y >> 16));
            v[it][4] = b2f((ushort)(raw.z & 0xffff)); v[it][5] = b2f((ushort)(raw.z >> 16));
            v[it][6] = b2f((ushort)(raw.w & 0xffff)); v[it][7] = b2f((ushort)(raw.w >> 16));
            #pragma unroll
            for (int j = 0; j < 8; ++j)
                if (i0 + j > t) v[it][j] = -INFINITY;
        }
    }

    float m = -INFINITY;
    #pragma unroll
    for (int it = 0; it < 2; ++it)
        #pragma unroll
        for (int j = 0; j < 8; ++j) m = fmaxf(m, v[it][j]);
    #pragma unroll
    for (int off = 32; off > 0; off >>= 1) m = fmaxf(m, __shfl_xor(m, off));

    float ssum = 0.0f;
    #pragma unroll
    for (int it = 0; it < 2; ++it)
        #pragma unroll
        for (int j = 0; j < 8; ++j)
            ssum += (v[it][j] > -1e37f) ? __expf(v[it][j] - m) : 0.0f;
    #pragma unroll
    for (int off = 32; off > 0; off >>= 1) ssum += __shfl_xor(ssum, off);

    if (ln == 0) stats[r0] = make_float2(m, 1.0f / ssum);
}

// ---------------------------------------------------------------------------
// proj5: proj4 + XCD-aware bijective block remap (T1). Each XCD owns the
// ty values with ty = xcd (mod 8): its 4 MB L2 pins the Cmat slice (256 KB)
// and the streamed Kmat (2 MB, re-read L2-hot per ty). Causal triangle stays
// balanced across XCDs (+-11%). Block internals identical to proj4.
// ---------------------------------------------------------------------------
template<bool SM>
__global__ __launch_bounds__(256, 4) void proj5(ushort* __restrict__ Lb,
                                                const ushort* __restrict__ Cmat,
                                                const ushort* __restrict__ Kmat,
                                                const float2* __restrict__ stats) {
    // --- XCD remap: bid -> (xcd, ty, sx), bijective on [0,4096) ---
    const int bid = blockIdx.y * 64 + blockIdx.x;
    const int xcd = bid & 7;
    const int idx = bid >> 3;                 // 0..511
    const int ty  = ((idx >> 6) << 3) + xcd;  // ty % 8 == xcd
    const int sx  = idx & 63;

    const int s0 = sx * 16;
    const int t0 = ty * 16;
    if (s0 > t0 + 15) return;            // fully masked tile

    __shared__ __align__(16) ushort Xs[16 * 648];   // 20736 B  [t][s:40][m]
    __shared__ __align__(16) float  Kp[16 * 260];   // 16640 B  [t][s:16][n]

    const int tid = threadIdx.x;
    const int wv = tid >> 6, ln = tid & 63;
    const int frow = ln & 15, quad = ln >> 4;

    // ---- stage X[t][s][m] <- Lb[m][t0+t][s0+s] (transpose head -> contiguous)
    #pragma unroll
    for (int it = 0; it < 4; ++it) {
        int slot = tid + it * 256;           // 1024 slots = 512 rows x 2 chunks
        int c    = slot & 1;                 // 16 B chunk -> 8 s values
        int row  = slot >> 1;                // n*16 + t
        int nn   = row >> 4, tl = row & 15;
        uint4 ld = *(const uint4*)(Lb + ((size_t)nn * T_DIM + t0 + tl) * S_DIM + s0 + c * 8);
        ushort u[8];
        u[0] = (ushort)(ld.x & 0xffff);  u[1] = (ushort)(ld.x >> 16);
        u[2] = (ushort)(ld.y & 0xffff);  u[3] = (ushort)(ld.y >> 16);
        u[4] = (ushort)(ld.z & 0xffff);  u[5] = (ushort)(ld.z >> 16);
        u[6] = (ushort)(ld.w & 0xffff);  u[7] = (ushort)(ld.w >> 16);
        if (SM) {
            const float2 ms = stats[nn * T_DIM + t0 + tl];
            const int tG = t0 + tl, sbase = s0 + c * 8;
            #pragma unroll
            for (int j = 0; j < 8; ++j) {
                float x = (sbase + j <= tG) ? __expf(b2f(u[j]) - ms.x) * ms.y : 0.0f;
                u[j] = f2b(x);
            }
        }
        ushort* xp = &Xs[tl * 648 + (c * 8) * 40 + nn];
        #pragma unroll
        for (int j = 0; j < 8; ++j) xp[j * 40] = u[j];
    }
    __syncthreads();

    #pragma unroll
    for (int mh = 0; mh < 2; ++mh) {
        // ---- K-phase: per s, D[n=16][t=16] = Kmat[s](n,m) x X(m,t,s); K=m=32
        #pragma unroll
        for (int k = 0; k < 4; ++k) {
            const int sl = wv * 4 + k;
            const short8 af = *(const short8*)(Kmat + (size_t)(s0 + sl) * 1024 + (mh * 16 + frow) * 32 + quad * 8);
            const short8 bf = *(const short8*)&Xs[frow * 648 + sl * 40 + quad * 8];
            floatx4 z = {0.f, 0.f, 0.f, 0.f};
            floatx4 d = __builtin_amdgcn_mfma_f32_16x16x32_bf16(af, bf, z, 0, 0, 0);
            // D rows (quad*4+r) = n, cols (frow) = t  ->  Kp[t][s][n]
            *(floatx4*)&Kp[frow * 260 + sl * 16 + quad * 4] = d;
        }
        __syncthreads();

        // ---- C-phase: per t, D[s=16][n=16] = X(s,m,t) x Cmat[t](n,m); add Kp, mask, store
        #pragma unroll
        for (int i = 0; i < 4; ++i) {
            const int tl = wv * 4 + i;
            const int tg = t0 + tl;
            const short8 bf = *(const short8*)(Cmat + (size_t)tg * 1024 + (mh * 16 + frow) * 32 + quad * 8);
            const short8 af = *(const short8*)&Xs[tl * 648 + frow * 40 + quad * 8];
            floatx4 z = {0.f, 0.f, 0.f, 0.f};
            floatx4 d = __builtin_amdgcn_mfma_f32_16x16x32_bf16(af, bf, z, 0, 0, 0);
            // D rows (quad*4+r) = s_local, cols (frow) = n
            float v[4];
            #pragma unroll
            for (int r = 0; r < 4; ++r) {
                const int sl = quad * 4 + r;
                float val = d[r] + Kp[tl * 260 + sl * 16 + frow];
                v[r] = (s0 + sl > tg) ? 0.0f : val;
            }
            uint2 stv;
            stv.x = (unsigned)pack_bf16(v[0], v[1]);
            stv.y = (unsigned)pack_bf16(v[2], v[3]);
            *(uint2*)&Lb[((size_t)(mh * 16 + frow) * T_DIM + tg) * S_DIM + s0 + quad * 4] = stv;
        }
        __syncthreads();   // Kp reused by next mh
    }
}

// ---------------------------------------------------------------------------
// av3: O = P V via MFMA. (unchanged; grid (n, tt) already gives XCD = n%8
// so each XCD's L2 pins 4 heads' Vt = 1 MB.)
// ---------------------------------------------------------------------------
__global__ __launch_bounds__(256, 4) void av3(const ushort* __restrict__ P,
                                              const ushort* __restrict__ Vt,
                                              float* __restrict__ O) {
    const int tid = threadIdx.x;
    const int wv = tid >> 6, ln = tid & 63;
    const int frow = ln & 15, quad = ln >> 4;
    const int n  = blockIdx.x;
    const int tt = 63 - blockIdx.y;      // big tiles first
    const int t0 = tt * 16;

    __shared__ ushort red[4][16][136];   // 17408 B bf16 partials

    const ushort* Pn  = P  + ((size_t)n * T_DIM + t0) * S_DIM;
    const ushort* Vtn = Vt + (size_t)n * D_HEAD * S_DIM;

    const int nsteps = (t0 + 47) >> 5;   // ceil((t0+16)/32)
    const int nclean = t0 >> 5;          // steps fully below diagonal

    floatx4 acc[8] = {};
    for (int sb = wv; sb < nsteps; sb += 4) {
        short8 a = *(const short8*)(Pn + (size_t)frow * S_DIM + sb * 32 + quad * 8);
        if (sb >= nclean) {
            const int tg  = t0 + frow;
            const int sg0 = sb * 32 + quad * 8;
            #pragma unroll
            for (int j = 0; j < 8; ++j)
                if (sg0 + j > tg) a[j] = 0;
        }
        #pragma unroll
        for (int dc = 0; dc < 8; ++dc) {
            const short8 b = *(const short8*)(Vtn + (size_t)(dc * 16 + frow) * S_DIM + sb * 32 + quad * 8);
            acc[dc] = __builtin_amdgcn_mfma_f32_16x16x32_bf16(a, b, acc[dc], 0, 0, 0);
        }
    }

    #pragma unroll
    for (int dc = 0; dc < 8; ++dc)
        #pragma unroll
        for (int r = 0; r < 4; ++r)
            red[wv][quad * 4 + r][dc * 16 + frow] = f2b(acc[dc][r]);
    __syncthreads();

    #pragma unroll
    for (int it = 0; it < 2; ++it) {
        int idx = tid + it * 256;
        int d4 = idx & 31, tr = idx >> 5;
        float4 v;
        v.x = b2f(red[0][tr][d4 * 4 + 0]) + b2f(red[1][tr][d4 * 4 + 0]) + b2f(red[2][tr][d4 * 4 + 0]) + b2f(red[3][tr][d4 * 4 + 0]);
        v.y = b2f(red[0][tr][d4 * 4 + 1]) + b2f(red[1][tr][d4 * 4 + 1]) + b2f(red[2][tr][d4 * 4 + 1]) + b2f(red[3][tr][d4 * 4 + 1]);
        v.z = b2f(red[0][tr][d4 * 4 + 2]) + b2f(red[1][tr][d4 * 4 + 2]) + b2f(red[2][tr][d4 * 4 + 2]) + b2f(red[3][tr][d4 * 4 + 2]);
        v.w = b2f(red[0][tr][d4 * 4 + 3]) + b2f(red[1][tr][d4 * 4 + 3]) + b2f(red[2][tr][d4 * 4 + 3]) + b2f(red[3][tr][d4 * 4 + 3]);
        *(float4*)&O[((size_t)n * T_DIM + t0 + tr) * D_HEAD + d4 * 4] = v;
    }
}

// ---------------------------------------------------------------------------
extern "C" void kernel_launch(void* const* d_in, const int* in_sizes, int n_in,
                              void* d_out, int out_size, void* d_ws, size_t ws_size,
                              hipStream_t stream) {
    const float* Q    = (const float*)d_in[0];
    const float* K    = (const float*)d_in[1];
    const float* V    = (const float*)d_in[2];
    const float* sw_pre  = (const float*)d_in[4];
    const float* qw1_pre = (const float*)d_in[5];
    const float* qw2_pre = (const float*)d_in[6];
    const float* kw1_pre = (const float*)d_in[7];
    const float* kw2_pre = (const float*)d_in[8];
    const float* qdd_pre = (const float*)d_in[9];
    const float* kdd_pre = (const float*)d_in[10];
    const float* sw_post  = (const float*)d_in[11];
    const float* qw1_post = (const float*)d_in[12];
    const float* qw2_post = (const float*)d_in[13];
    const float* kw1_post = (const float*)d_in[14];
    const float* kw2_post = (const float*)d_in[15];
    const float* qdd_post = (const float*)d_in[16];
    const float* kdd_post = (const float*)d_in[17];

    // ws: L bf16 [32][1024][1024] = 64 MB, then Vt bf16 [32][128][1024] = 8 MB
    ushort* Lb = (ushort*)d_ws;
    ushort* Vt = (ushort*)((char*)d_ws + (size_t)N_HEADS * T_DIM * S_DIM * 2);
    float*  O  = (float*)d_out;

    // d_out scratch (16 MB): mats in first 8 MB, softmax stats after.
    // Both fully consumed before av3 overwrites d_out.
    ushort* mats  = (ushort*)d_out;
    ushort* Cpre  = mats + 0 * 1024 * 1024;
    ushort* Kpre  = mats + 1 * 1024 * 1024;
    ushort* Cpost = mats + 2 * 1024 * 1024;
    ushort* Kpost = mats + 3 * 1024 * 1024;
    float2* stats = (float2*)((char*)d_out + (size_t)8 * 1024 * 1024);

    mat4_kernel<<<dim3(1024, 4), 256, 0, stream>>>(
        sw_pre, qw1_pre, qw2_pre, qdd_pre, kw1_pre, kw2_pre, kdd_pre,
        sw_post, qw1_post, qw2_post, qdd_post, kw1_post, kw2_post, kdd_post, mats);
    vt_kernel<<<dim3(16, 32), 256, 0, stream>>>(V, Vt);

    qk_mfma<<<dim3(16, 16, 32), 256, 0, stream>>>(Q, K, Lb);
    proj5<false><<<dim3(64, 64), 256, 0, stream>>>(Lb, Cpre, Kpre, nullptr);
    rowstat<<<dim3(8192), 256, 0, stream>>>(Lb, stats);
    proj5<true><<<dim3(64, 64), 256, 0, stream>>>(Lb, Cpost, Kpost, stats);
    av3<<<dim3(32, 64), 256, 0, stream>>>(Lb, Vt, O);
}

// Round 6
// 259.662 us; speedup vs baseline: 1.1699x; 1.0114x over previous
//
#include <hip/hip_runtime.h>
#include <hip/hip_bf16.h>
#include <cstdint>
#include <cstddef>

#define T_DIM 1024
#define S_DIM 1024
#define N_HEADS 32
#define D_HEAD 128

typedef __attribute__((ext_vector_type(8))) short short8;
typedef __attribute__((ext_vector_type(4))) float floatx4;

__device__ inline int pack_bf16(float a, float b) {
    __hip_bfloat162 h = __float22bfloat162_rn(make_float2(a, b));
    int r; __builtin_memcpy(&r, &h, 4); return r;
}
__device__ inline ushort f2b(float x) {
    __hip_bfloat16 h = __float2bfloat16(x);
    ushort u; __builtin_memcpy(&u, &h, 2); return u;
}
__device__ inline float b2f(ushort u) {
    unsigned int v = ((unsigned int)u) << 16;
    float f; __builtin_memcpy(&f, &v, 4); return f;
}

// ---------------------------------------------------------------------------
// tobf16: Qb/Kb bf16 <- Q/K fp32, straight elementwise. 2048 blocks.
// ---------------------------------------------------------------------------
__global__ __launch_bounds__(256) void tobf16(const float* __restrict__ Q,
                                              const float* __restrict__ K,
                                              ushort* __restrict__ Qb,
                                              ushort* __restrict__ Kb) {
    const size_t gid = (size_t)blockIdx.x * 256 + threadIdx.x;   // 0..524287
    #pragma unroll
    for (int j = 0; j < 2; ++j) {
        size_t i = gid + (size_t)j * 524288;                      // float4 idx
        float4 q = ((const float4*)Q)[i];
        int2 qp; qp.x = pack_bf16(q.x, q.y); qp.y = pack_bf16(q.z, q.w);
        ((int2*)Qb)[i] = qp;
        float4 k = ((const float4*)K)[i];
        int2 kp; kp.x = pack_bf16(k.x, k.y); kp.y = pack_bf16(k.z, k.w);
        ((int2*)Kb)[i] = kp;
    }
}

// ---------------------------------------------------------------------------
// Vt[n][d][s] bf16 <- V[n][s][d] fp32.  64s x 128d tile per block. (unchanged)
// ---------------------------------------------------------------------------
__global__ __launch_bounds__(256) void vt_kernel(const float* __restrict__ V,
                                                 ushort* __restrict__ Vt) {
    const int s0 = blockIdx.x * 64;
    const int n  = blockIdx.y;
    __shared__ float lds[128 * 65];

    const int tid = threadIdx.x;
    const float* Vn = V + ((size_t)n * S_DIM + s0) * D_HEAD;

    #pragma unroll
    for (int it = 0; it < 8; ++it) {
        int idx = tid + it * 256;
        int d4 = idx & 31, s = idx >> 5;
        float4 v = *(const float4*)(Vn + (size_t)s * D_HEAD + d4 * 4);
        lds[(d4 * 4 + 0) * 65 + s] = v.x;
        lds[(d4 * 4 + 1) * 65 + s] = v.y;
        lds[(d4 * 4 + 2) * 65 + s] = v.z;
        lds[(d4 * 4 + 3) * 65 + s] = v.w;
    }
    __syncthreads();

    ushort* Vtn = Vt + (size_t)n * D_HEAD * S_DIM;
    #pragma unroll
    for (int it = 0; it < 4; ++it) {
        int idx = tid + it * 256;
        int sg = idx & 7, d = idx >> 3;
        const float* src = &lds[d * 65 + sg * 8];
        int4 o;
        o.x = pack_bf16(src[0], src[1]);
        o.y = pack_bf16(src[2], src[3]);
        o.z = pack_bf16(src[4], src[5]);
        o.w = pack_bf16(src[6], src[7]);
        *(int4*)&Vtn[(size_t)d * S_DIM + s0 + sg * 8] = o;
    }
}

// ---------------------------------------------------------------------------
// qk2: logits (bf16) via MFMA, 64x64 causal tiles, bf16 inputs.
// Staging: one uint4 load = one swizzled 16 B LDS granule (same verified
// fragment layout as before; chunk index qw == read-side quad). XCD-grouped
// 1D grid: xcd = bid&7 owns (n,tt) pairs with pair%8==xcd; st fastest ->
// Q tile L2-pinned per XCD across its 16 st-steps.
// ---------------------------------------------------------------------------
__global__ __launch_bounds__(256, 2) void qk2(const ushort* __restrict__ Qb,
                                              const ushort* __restrict__ Kb,
                                              ushort* __restrict__ Lb) {
    const int bid  = blockIdx.x;
    const int xcd  = bid & 7;
    const int i    = bid >> 3;             // 0..1023
    const int st   = i & 15;
    const int pair = (i >> 4) * 8 + xcd;   // 0..511 bijective
    const int n    = pair >> 4;
    const int tt   = pair & 15;
    if (st > tt) return;

    __shared__ int Qt[64 * 64];
    __shared__ int Kt[64 * 64];

    const int tid = threadIdx.x;
    const int wv = tid >> 6, ln = tid & 63;
    const int frow = ln & 15, quad = ln >> 4;

    const ushort* Qn = Qb + ((size_t)n * T_DIM + (size_t)tt * 64) * D_HEAD;
    const ushort* Kn = Kb + ((size_t)n * S_DIM + (size_t)st * 64) * D_HEAD;

    #pragma unroll
    for (int rep = 0; rep < 8; ++rep) {
        int idx = (tid + rep * 256) & 1023;
        int row = idx >> 4;
        int c   = idx & 15;                 // 16 B chunk = 8 bf16
        int kb  = c >> 2, qw = c & 3;
        int dst = row * 64 + kb * 16 + ((qw * 4) ^ (4 * (row & 3)));
        if (rep < 4) {
            uint4 v = *(const uint4*)(Qn + (size_t)row * D_HEAD + c * 8);
            *(uint4*)&Qt[dst] = v;
        } else {
            uint4 v = *(const uint4*)(Kn + (size_t)row * D_HEAD + c * 8);
            *(uint4*)&Kt[dst] = v;
        }
    }
    __syncthreads();

    const int swz = 4 * (frow & 3);
    floatx4 acc[4] = {};
    #pragma unroll
    for (int kb = 0; kb < 4; ++kb) {
        const short8 af = *(const short8*)&Qt[(wv * 16 + frow) * 64 + kb * 16 + ((quad * 4) ^ swz)];
        #pragma unroll
        for (int si = 0; si < 4; ++si) {
            const short8 bf = *(const short8*)&Kt[(si * 16 + frow) * 64 + kb * 16 + ((quad * 4) ^ swz)];
            acc[si] = __builtin_amdgcn_mfma_f32_16x16x32_bf16(af, bf, acc[si], 0, 0, 0);
        }
    }
    __syncthreads();                    // Qt dead -> reuse as output tile

    ushort* Ot = (ushort*)Qt;           // [64][72] bf16
    #pragma unroll
    for (int si = 0; si < 4; ++si)
        #pragma unroll
        for (int r = 0; r < 4; ++r)
            Ot[(wv * 16 + quad * 4 + r) * 72 + si * 16 + frow] = f2b(acc[si][r]);
    __syncthreads();

    #pragma unroll
    for (int it = 0; it < 2; ++it) {
        int idx = tid + it * 256;
        int row = idx >> 3, col = idx & 7;
        int4 v = *(const int4*)&Ot[row * 72 + col * 8];
        *(int4*)&Lb[((size_t)n * T_DIM + tt * 64 + row) * S_DIM + st * 64 + col * 8] = v;
    }
}

// ---------------------------------------------------------------------------
// Precompute all four 32x32 mixing-matrix families in one launch. (unchanged)
// ---------------------------------------------------------------------------
__global__ __launch_bounds__(256) void mat4_kernel(
        const float* __restrict__ sw_pre,  const float* __restrict__ qw1_pre,
        const float* __restrict__ qw2_pre, const float* __restrict__ qdd_pre,
        const float* __restrict__ kw1_pre, const float* __restrict__ kw2_pre,
        const float* __restrict__ kdd_pre,
        const float* __restrict__ sw_post,  const float* __restrict__ qw1_post,
        const float* __restrict__ qw2_post, const float* __restrict__ qdd_post,
        const float* __restrict__ kw1_post, const float* __restrict__ kw2_post,
        const float* __restrict__ kdd_post,
        ushort* __restrict__ mats) {
    const float *sw, *w1, *w2, *dd;
    float idadd;
    switch (blockIdx.y) {
        case 0:  sw = sw_pre;  w1 = qw1_pre;  w2 = qw2_pre;  dd = qdd_pre;  idadd = 1.0f; break;
        case 1:  sw = nullptr; w1 = kw1_pre;  w2 = kw2_pre;  dd = kdd_pre;  idadd = 0.0f; break;
        case 2:  sw = sw_post; w1 = qw1_post; w2 = qw2_post; dd = qdd_post; idadd = 1.0f; break;
        default: sw = nullptr; w1 = kw1_post; w2 = kw2_post; dd = kdd_post; idadd = 0.0f; break;
    }
    ushort* out = mats + (size_t)blockIdx.y * 1024 * 1024;

    const int t = blockIdx.x;
    const int tid = threadIdx.x;
    const int m = tid >> 3;
    const int n0 = (tid & 7) * 4;

    const float w2m0 = w2[t * 64 + m];
    const float w2m1 = w2[t * 64 + 32 + m];
    const float ddm  = dd[t * 32 + m];

    float v[4];
    #pragma unroll
    for (int j = 0; j < 4; ++j) {
        int n = n0 + j;
        float r = w1[t * 64 + n] * w2m0 + w1[t * 64 + 32 + n] * w2m1;
        if (sw) r += sw[n * 32 + m];
        if (n == m) r += idadd + ddm;
        v[j] = r;
    }
    int p0 = pack_bf16(v[0], v[1]);
    int p1 = pack_bf16(v[2], v[3]);
    int2 st = make_int2(p0, p1);
    *(int2*)&out[(size_t)t * 1024 + m * 32 + n0] = st;
}

// ---------------------------------------------------------------------------
// rowstat: per-(n,t) softmax stats. One wave per row, 4 rows/block. (unchanged)
// ---------------------------------------------------------------------------
__global__ __launch_bounds__(256) void rowstat(const ushort* __restrict__ Lb,
                                               float2* __restrict__ stats) {
    const int wv = threadIdx.x >> 6;
    const int ln = threadIdx.x & 63;
    const int r0 = blockIdx.x * 4 + wv;       // n*1024 + t
    const int t  = r0 & (T_DIM - 1);
    const ushort* row = Lb + (size_t)r0 * S_DIM;

    float v[2][8];
    #pragma unroll
    for (int it = 0; it < 2; ++it) {
        const int i0 = it * 512 + ln * 8;
        #pragma unroll
        for (int j = 0; j < 8; ++j) v[it][j] = -INFINITY;
        if (i0 <= t) {
            uint4 raw = *(const uint4*)&row[i0];
            v[it][0] = b2f((ushort)(raw.x & 0xffff)); v[it][1] = b2f((ushort)(raw.x >> 16));
            v[it][2] = b2f((ushort)(raw.y & 0xffff)); v[it][3] = b2f((ushort)(raw.y >> 16));
            v[it][4] = b2f((ushort)(raw.z & 0xffff)); v[it][5] = b2f((ushort)(raw.z >> 16));
            v[it][6] = b2f((ushort)(raw.w & 0xffff)); v[it][7] = b2f((ushort)(raw.w >> 16));
            #pragma unroll
            for (int j = 0; j < 8; ++j)
                if (i0 + j > t) v[it][j] = -INFINITY;
        }
    }

    float m = -INFINITY;
    #pragma unroll
    for (int it = 0; it < 2; ++it)
        #pragma unroll
        for (int j = 0; j < 8; ++j) m = fmaxf(m, v[it][j]);
    #pragma unroll
    for (int off = 32; off > 0; off >>= 1) m = fmaxf(m, __shfl_xor(m, off));

    float ssum = 0.0f;
    #pragma unroll
    for (int it = 0; it < 2; ++it)
        #pragma unroll
        for (int j = 0; j < 8; ++j)
            ssum += (v[it][j] > -1e37f) ? __expf(v[it][j] - m) : 0.0f;
    #pragma unroll
    for (int off = 32; off > 0; off >>= 1) ssum += __shfl_xor(ssum, off);

    if (ln == 0) stats[r0] = make_float2(m, 1.0f / ssum);
}

// ---------------------------------------------------------------------------
// proj5: fused cross-head projection + XCD-aware bijective remap. (unchanged)
// ---------------------------------------------------------------------------
template<bool SM>
__global__ __launch_bounds__(256, 4) void proj5(ushort* __restrict__ Lb,
                                                const ushort* __restrict__ Cmat,
                                                const ushort* __restrict__ Kmat,
                                                const float2* __restrict__ stats) {
    const int bid = blockIdx.y * 64 + blockIdx.x;
    const int xcd = bid & 7;
    const int idx = bid >> 3;                 // 0..511
    const int ty  = ((idx >> 6) << 3) + xcd;  // ty % 8 == xcd
    const int sx  = idx & 63;

    const int s0 = sx * 16;
    const int t0 = ty * 16;
    if (s0 > t0 + 15) return;

    __shared__ __align__(16) ushort Xs[16 * 648];   // 20736 B  [t][s:40][m]
    __shared__ __align__(16) float  Kp[16 * 260];   // 16640 B  [t][s:16][n]

    const int tid = threadIdx.x;
    const int wv = tid >> 6, ln = tid & 63;
    const int frow = ln & 15, quad = ln >> 4;

    #pragma unroll
    for (int it = 0; it < 4; ++it) {
        int slot = tid + it * 256;
        int c    = slot & 1;
        int row  = slot >> 1;
        int nn   = row >> 4, tl = row & 15;
        uint4 ld = *(const uint4*)(Lb + ((size_t)nn * T_DIM + t0 + tl) * S_DIM + s0 + c * 8);
        ushort u[8];
        u[0] = (ushort)(ld.x & 0xffff);  u[1] = (ushort)(ld.x >> 16);
        u[2] = (ushort)(ld.y & 0xffff);  u[3] = (ushort)(ld.y >> 16);
        u[4] = (ushort)(ld.z & 0xffff);  u[5] = (ushort)(ld.z >> 16);
        u[6] = (ushort)(ld.w & 0xffff);  u[7] = (ushort)(ld.w >> 16);
        if (SM) {
            const float2 ms = stats[nn * T_DIM + t0 + tl];
            const int tG = t0 + tl, sbase = s0 + c * 8;
            #pragma unroll
            for (int j = 0; j < 8; ++j) {
                float x = (sbase + j <= tG) ? __expf(b2f(u[j]) - ms.x) * ms.y : 0.0f;
                u[j] = f2b(x);
            }
        }
        ushort* xp = &Xs[tl * 648 + (c * 8) * 40 + nn];
        #pragma unroll
        for (int j = 0; j < 8; ++j) xp[j * 40] = u[j];
    }
    __syncthreads();

    #pragma unroll
    for (int mh = 0; mh < 2; ++mh) {
        #pragma unroll
        for (int k = 0; k < 4; ++k) {
            const int sl = wv * 4 + k;
            const short8 af = *(const short8*)(Kmat + (size_t)(s0 + sl) * 1024 + (mh * 16 + frow) * 32 + quad * 8);
            const short8 bf = *(const short8*)&Xs[frow * 648 + sl * 40 + quad * 8];
            floatx4 z = {0.f, 0.f, 0.f, 0.f};
            floatx4 d = __builtin_amdgcn_mfma_f32_16x16x32_bf16(af, bf, z, 0, 0, 0);
            *(floatx4*)&Kp[frow * 260 + sl * 16 + quad * 4] = d;
        }
        __syncthreads();

        #pragma unroll
        for (int i = 0; i < 4; ++i) {
            const int tl = wv * 4 + i;
            const int tg = t0 + tl;
            const short8 bf = *(const short8*)(Cmat + (size_t)tg * 1024 + (mh * 16 + frow) * 32 + quad * 8);
            const short8 af = *(const short8*)&Xs[tl * 648 + frow * 40 + quad * 8];
            floatx4 z = {0.f, 0.f, 0.f, 0.f};
            floatx4 d = __builtin_amdgcn_mfma_f32_16x16x32_bf16(af, bf, z, 0, 0, 0);
            float v[4];
            #pragma unroll
            for (int r = 0; r < 4; ++r) {
                const int sl = quad * 4 + r;
                float val = d[r] + Kp[tl * 260 + sl * 16 + frow];
                v[r] = (s0 + sl > tg) ? 0.0f : val;
            }
            uint2 stv;
            stv.x = (unsigned)pack_bf16(v[0], v[1]);
            stv.y = (unsigned)pack_bf16(v[2], v[3]);
            *(uint2*)&Lb[((size_t)(mh * 16 + frow) * T_DIM + tg) * S_DIM + s0 + quad * 4] = stv;
        }
        __syncthreads();
    }
}

// ---------------------------------------------------------------------------
// av3: O = P V via MFMA. (unchanged)
// ---------------------------------------------------------------------------
__global__ __launch_bounds__(256, 4) void av3(const ushort* __restrict__ P,
                                              const ushort* __restrict__ Vt,
                                              float* __restrict__ O) {
    const int tid = threadIdx.x;
    const int wv = tid >> 6, ln = tid & 63;
    const int frow = ln & 15, quad = ln >> 4;
    const int n  = blockIdx.x;
    const int tt = 63 - blockIdx.y;      // big tiles first
    const int t0 = tt * 16;

    __shared__ ushort red[4][16][136];   // 17408 B bf16 partials

    const ushort* Pn  = P  + ((size_t)n * T_DIM + t0) * S_DIM;
    const ushort* Vtn = Vt + (size_t)n * D_HEAD * S_DIM;

    const int nsteps = (t0 + 47) >> 5;   // ceil((t0+16)/32)
    const int nclean = t0 >> 5;          // steps fully below diagonal

    floatx4 acc[8] = {};
    for (int sb = wv; sb < nsteps; sb += 4) {
        short8 a = *(const short8*)(Pn + (size_t)frow * S_DIM + sb * 32 + quad * 8);
        if (sb >= nclean) {
            const int tg  = t0 + frow;
            const int sg0 = sb * 32 + quad * 8;
            #pragma unroll
            for (int j = 0; j < 8; ++j)
                if (sg0 + j > tg) a[j] = 0;
        }
        #pragma unroll
        for (int dc = 0; dc < 8; ++dc) {
            const short8 b = *(const short8*)(Vtn + (size_t)(dc * 16 + frow) * S_DIM + sb * 32 + quad * 8);
            acc[dc] = __builtin_amdgcn_mfma_f32_16x16x32_bf16(a, b, acc[dc], 0, 0, 0);
        }
    }

    #pragma unroll
    for (int dc = 0; dc < 8; ++dc)
        #pragma unroll
        for (int r = 0; r < 4; ++r)
            red[wv][quad * 4 + r][dc * 16 + frow] = f2b(acc[dc][r]);
    __syncthreads();

    #pragma unroll
    for (int it = 0; it < 2; ++it) {
        int idx = tid + it * 256;
        int d4 = idx & 31, tr = idx >> 5;
        float4 v;
        v.x = b2f(red[0][tr][d4 * 4 + 0]) + b2f(red[1][tr][d4 * 4 + 0]) + b2f(red[2][tr][d4 * 4 + 0]) + b2f(red[3][tr][d4 * 4 + 0]);
        v.y = b2f(red[0][tr][d4 * 4 + 1]) + b2f(red[1][tr][d4 * 4 + 1]) + b2f(red[2][tr][d4 * 4 + 1]) + b2f(red[3][tr][d4 * 4 + 1]);
        v.z = b2f(red[0][tr][d4 * 4 + 2]) + b2f(red[1][tr][d4 * 4 + 2]) + b2f(red[2][tr][d4 * 4 + 2]) + b2f(red[3][tr][d4 * 4 + 2]);
        v.w = b2f(red[0][tr][d4 * 4 + 3]) + b2f(red[1][tr][d4 * 4 + 3]) + b2f(red[2][tr][d4 * 4 + 3]) + b2f(red[3][tr][d4 * 4 + 3]);
        *(float4*)&O[((size_t)n * T_DIM + t0 + tr) * D_HEAD + d4 * 4] = v;
    }
}

// ---------------------------------------------------------------------------
extern "C" void kernel_launch(void* const* d_in, const int* in_sizes, int n_in,
                              void* d_out, int out_size, void* d_ws, size_t ws_size,
                              hipStream_t stream) {
    const float* Q    = (const float*)d_in[0];
    const float* K    = (const float*)d_in[1];
    const float* V    = (const float*)d_in[2];
    const float* sw_pre  = (const float*)d_in[4];
    const float* qw1_pre = (const float*)d_in[5];
    const float* qw2_pre = (const float*)d_in[6];
    const float* kw1_pre = (const float*)d_in[7];
    const float* kw2_pre = (const float*)d_in[8];
    const float* qdd_pre = (const float*)d_in[9];
    const float* kdd_pre = (const float*)d_in[10];
    const float* sw_post  = (const float*)d_in[11];
    const float* qw1_post = (const float*)d_in[12];
    const float* qw2_post = (const float*)d_in[13];
    const float* kw1_post = (const float*)d_in[14];
    const float* kw2_post = (const float*)d_in[15];
    const float* qdd_post = (const float*)d_in[16];
    const float* kdd_post = (const float*)d_in[17];

    // ws layout: Lb 64 MB | Vt 8 MB | Qb 8 MB | Kb 8 MB  (= 88 MB total)
    ushort* Lb = (ushort*)d_ws;
    ushort* Vt = (ushort*)((char*)d_ws + (size_t)64 * 1024 * 1024);
    ushort* Qb = (ushort*)((char*)d_ws + (size_t)72 * 1024 * 1024);
    ushort* Kb = (ushort*)((char*)d_ws + (size_t)80 * 1024 * 1024);
    float*  O  = (float*)d_out;

    // d_out scratch (16 MB): mats in first 8 MB, softmax stats after.
    // Both fully consumed before av3 overwrites d_out.
    ushort* mats  = (ushort*)d_out;
    ushort* Cpre  = mats + 0 * 1024 * 1024;
    ushort* Kpre  = mats + 1 * 1024 * 1024;
    ushort* Cpost = mats + 2 * 1024 * 1024;
    ushort* Kpost = mats + 3 * 1024 * 1024;
    float2* stats = (float2*)((char*)d_out + (size_t)8 * 1024 * 1024);

    mat4_kernel<<<dim3(1024, 4), 256, 0, stream>>>(
        sw_pre, qw1_pre, qw2_pre, qdd_pre, kw1_pre, kw2_pre, kdd_pre,
        sw_post, qw1_post, qw2_post, qdd_post, kw1_post, kw2_post, kdd_post, mats);
    tobf16<<<dim3(2048), 256, 0, stream>>>(Q, K, Qb, Kb);
    vt_kernel<<<dim3(16, 32), 256, 0, stream>>>(V, Vt);

    qk2<<<dim3(8192), 256, 0, stream>>>(Qb, Kb, Lb);
    proj5<false><<<dim3(64, 64), 256, 0, stream>>>(Lb, Cpre, Kpre, nullptr);
    rowstat<<<dim3(8192), 256, 0, stream>>>(Lb, stats);
    proj5<true><<<dim3(64, 64), 256, 0, stream>>>(Lb, Cpost, Kpost, stats);
    av3<<<dim3(32, 64), 256, 0, stream>>>(Lb, Vt, O);
}

// Round 7
// 245.988 us; speedup vs baseline: 1.2349x; 1.0556x over previous
//
#include <hip/hip_runtime.h>
#include <hip/hip_bf16.h>
#include <cstdint>
#include <cstddef>

#define T_DIM 1024
#define S_DIM 1024
#define N_HEADS 32
#define D_HEAD 128

typedef __attribute__((ext_vector_type(8))) short short8;
typedef __attribute__((ext_vector_type(4))) float floatx4;

__device__ inline int pack_bf16(float a, float b) {
    __hip_bfloat162 h = __float22bfloat162_rn(make_float2(a, b));
    int r; __builtin_memcpy(&r, &h, 4); return r;
}
__device__ inline ushort f2b(float x) {
    __hip_bfloat16 h = __float2bfloat16(x);
    ushort u; __builtin_memcpy(&u, &h, 2); return u;
}
__device__ inline float b2f(ushort u) {
    unsigned int v = ((unsigned int)u) << 16;
    float f; __builtin_memcpy(&f, &v, 4); return f;
}

// ---------------------------------------------------------------------------
// tobf16: Qb/Kb bf16 <- Q/K fp32, straight elementwise. (unchanged)
// ---------------------------------------------------------------------------
__global__ __launch_bounds__(256) void tobf16(const float* __restrict__ Q,
                                              const float* __restrict__ K,
                                              ushort* __restrict__ Qb,
                                              ushort* __restrict__ Kb) {
    const size_t gid = (size_t)blockIdx.x * 256 + threadIdx.x;   // 0..524287
    #pragma unroll
    for (int j = 0; j < 2; ++j) {
        size_t i = gid + (size_t)j * 524288;                      // float4 idx
        float4 q = ((const float4*)Q)[i];
        int2 qp; qp.x = pack_bf16(q.x, q.y); qp.y = pack_bf16(q.z, q.w);
        ((int2*)Qb)[i] = qp;
        float4 k = ((const float4*)K)[i];
        int2 kp; kp.x = pack_bf16(k.x, k.y); kp.y = pack_bf16(k.z, k.w);
        ((int2*)Kb)[i] = kp;
    }
}

// ---------------------------------------------------------------------------
// Vt[n][d][s] bf16 <- V[n][s][d] fp32.  64s x 128d tile per block. (unchanged)
// ---------------------------------------------------------------------------
__global__ __launch_bounds__(256) void vt_kernel(const float* __restrict__ V,
                                                 ushort* __restrict__ Vt) {
    const int s0 = blockIdx.x * 64;
    const int n  = blockIdx.y;
    __shared__ float lds[128 * 65];

    const int tid = threadIdx.x;
    const float* Vn = V + ((size_t)n * S_DIM + s0) * D_HEAD;

    #pragma unroll
    for (int it = 0; it < 8; ++it) {
        int idx = tid + it * 256;
        int d4 = idx & 31, s = idx >> 5;
        float4 v = *(const float4*)(Vn + (size_t)s * D_HEAD + d4 * 4);
        lds[(d4 * 4 + 0) * 65 + s] = v.x;
        lds[(d4 * 4 + 1) * 65 + s] = v.y;
        lds[(d4 * 4 + 2) * 65 + s] = v.z;
        lds[(d4 * 4 + 3) * 65 + s] = v.w;
    }
    __syncthreads();

    ushort* Vtn = Vt + (size_t)n * D_HEAD * S_DIM;
    #pragma unroll
    for (int it = 0; it < 4; ++it) {
        int idx = tid + it * 256;
        int sg = idx & 7, d = idx >> 3;
        const float* src = &lds[d * 65 + sg * 8];
        int4 o;
        o.x = pack_bf16(src[0], src[1]);
        o.y = pack_bf16(src[2], src[3]);
        o.z = pack_bf16(src[4], src[5]);
        o.w = pack_bf16(src[6], src[7]);
        *(int4*)&Vtn[(size_t)d * S_DIM + s0 + sg * 8] = o;
    }
}

// ---------------------------------------------------------------------------
// qk2: logits (bf16) via MFMA, 64x64 causal tiles, bf16 inputs. (unchanged)
// ---------------------------------------------------------------------------
__global__ __launch_bounds__(256, 2) void qk2(const ushort* __restrict__ Qb,
                                              const ushort* __restrict__ Kb,
                                              ushort* __restrict__ Lb) {
    const int bid  = blockIdx.x;
    const int xcd  = bid & 7;
    const int i    = bid >> 3;             // 0..1023
    const int st   = i & 15;
    const int pair = (i >> 4) * 8 + xcd;   // 0..511 bijective
    const int n    = pair >> 4;
    const int tt   = pair & 15;
    if (st > tt) return;

    __shared__ int Qt[64 * 64];
    __shared__ int Kt[64 * 64];

    const int tid = threadIdx.x;
    const int wv = tid >> 6, ln = tid & 63;
    const int frow = ln & 15, quad = ln >> 4;

    const ushort* Qn = Qb + ((size_t)n * T_DIM + (size_t)tt * 64) * D_HEAD;
    const ushort* Kn = Kb + ((size_t)n * S_DIM + (size_t)st * 64) * D_HEAD;

    #pragma unroll
    for (int rep = 0; rep < 8; ++rep) {
        int idx = (tid + rep * 256) & 1023;
        int row = idx >> 4;
        int c   = idx & 15;                 // 16 B chunk = 8 bf16
        int kb  = c >> 2, qw = c & 3;
        int dst = row * 64 + kb * 16 + ((qw * 4) ^ (4 * (row & 3)));
        if (rep < 4) {
            uint4 v = *(const uint4*)(Qn + (size_t)row * D_HEAD + c * 8);
            *(uint4*)&Qt[dst] = v;
        } else {
            uint4 v = *(const uint4*)(Kn + (size_t)row * D_HEAD + c * 8);
            *(uint4*)&Kt[dst] = v;
        }
    }
    __syncthreads();

    const int swz = 4 * (frow & 3);
    floatx4 acc[4] = {};
    #pragma unroll
    for (int kb = 0; kb < 4; ++kb) {
        const short8 af = *(const short8*)&Qt[(wv * 16 + frow) * 64 + kb * 16 + ((quad * 4) ^ swz)];
        #pragma unroll
        for (int si = 0; si < 4; ++si) {
            const short8 bf = *(const short8*)&Kt[(si * 16 + frow) * 64 + kb * 16 + ((quad * 4) ^ swz)];
            acc[si] = __builtin_amdgcn_mfma_f32_16x16x32_bf16(af, bf, acc[si], 0, 0, 0);
        }
    }
    __syncthreads();                    // Qt dead -> reuse as output tile

    ushort* Ot = (ushort*)Qt;           // [64][72] bf16
    #pragma unroll
    for (int si = 0; si < 4; ++si)
        #pragma unroll
        for (int r = 0; r < 4; ++r)
            Ot[(wv * 16 + quad * 4 + r) * 72 + si * 16 + frow] = f2b(acc[si][r]);
    __syncthreads();

    #pragma unroll
    for (int it = 0; it < 2; ++it) {
        int idx = tid + it * 256;
        int row = idx >> 3, col = idx & 7;
        int4 v = *(const int4*)&Ot[row * 72 + col * 8];
        *(int4*)&Lb[((size_t)n * T_DIM + tt * 64 + row) * S_DIM + st * 64 + col * 8] = v;
    }
}

// ---------------------------------------------------------------------------
// Precompute all four 32x32 mixing-matrix families in one launch. (unchanged)
// ---------------------------------------------------------------------------
__global__ __launch_bounds__(256) void mat4_kernel(
        const float* __restrict__ sw_pre,  const float* __restrict__ qw1_pre,
        const float* __restrict__ qw2_pre, const float* __restrict__ qdd_pre,
        const float* __restrict__ kw1_pre, const float* __restrict__ kw2_pre,
        const float* __restrict__ kdd_pre,
        const float* __restrict__ sw_post,  const float* __restrict__ qw1_post,
        const float* __restrict__ qw2_post, const float* __restrict__ qdd_post,
        const float* __restrict__ kw1_post, const float* __restrict__ kw2_post,
        const float* __restrict__ kdd_post,
        ushort* __restrict__ mats) {
    const float *sw, *w1, *w2, *dd;
    float idadd;
    switch (blockIdx.y) {
        case 0:  sw = sw_pre;  w1 = qw1_pre;  w2 = qw2_pre;  dd = qdd_pre;  idadd = 1.0f; break;
        case 1:  sw = nullptr; w1 = kw1_pre;  w2 = kw2_pre;  dd = kdd_pre;  idadd = 0.0f; break;
        case 2:  sw = sw_post; w1 = qw1_post; w2 = qw2_post; dd = qdd_post; idadd = 1.0f; break;
        default: sw = nullptr; w1 = kw1_post; w2 = kw2_post; dd = kdd_post; idadd = 0.0f; break;
    }
    ushort* out = mats + (size_t)blockIdx.y * 1024 * 1024;

    const int t = blockIdx.x;
    const int tid = threadIdx.x;
    const int m = tid >> 3;
    const int n0 = (tid & 7) * 4;

    const float w2m0 = w2[t * 64 + m];
    const float w2m1 = w2[t * 64 + 32 + m];
    const float ddm  = dd[t * 32 + m];

    float v[4];
    #pragma unroll
    for (int j = 0; j < 4; ++j) {
        int n = n0 + j;
        float r = w1[t * 64 + n] * w2m0 + w1[t * 64 + 32 + n] * w2m1;
        if (sw) r += sw[n * 32 + m];
        if (n == m) r += idadd + ddm;
        v[j] = r;
    }
    int p0 = pack_bf16(v[0], v[1]);
    int p1 = pack_bf16(v[2], v[3]);
    int2 st = make_int2(p0, p1);
    *(int2*)&out[(size_t)t * 1024 + m * 32 + n0] = st;
}

// ---------------------------------------------------------------------------
// rowstat: per-(n,t) softmax stats. One wave per row, 4 rows/block. (unchanged)
// ---------------------------------------------------------------------------
__global__ __launch_bounds__(256) void rowstat(const ushort* __restrict__ Lb,
                                               float2* __restrict__ stats) {
    const int wv = threadIdx.x >> 6;
    const int ln = threadIdx.x & 63;
    const int r0 = blockIdx.x * 4 + wv;       // n*1024 + t
    const int t  = r0 & (T_DIM - 1);
    const ushort* row = Lb + (size_t)r0 * S_DIM;

    float v[2][8];
    #pragma unroll
    for (int it = 0; it < 2; ++it) {
        const int i0 = it * 512 + ln * 8;
        #pragma unroll
        for (int j = 0; j < 8; ++j) v[it][j] = -INFINITY;
        if (i0 <= t) {
            uint4 raw = *(const uint4*)&row[i0];
            v[it][0] = b2f((ushort)(raw.x & 0xffff)); v[it][1] = b2f((ushort)(raw.x >> 16));
            v[it][2] = b2f((ushort)(raw.y & 0xffff)); v[it][3] = b2f((ushort)(raw.y >> 16));
            v[it][4] = b2f((ushort)(raw.z & 0xffff)); v[it][5] = b2f((ushort)(raw.z >> 16));
            v[it][6] = b2f((ushort)(raw.w & 0xffff)); v[it][7] = b2f((ushort)(raw.w >> 16));
            #pragma unroll
            for (int j = 0; j < 8; ++j)
                if (i0 + j > t) v[it][j] = -INFINITY;
        }
    }

    float m = -INFINITY;
    #pragma unroll
    for (int it = 0; it < 2; ++it)
        #pragma unroll
        for (int j = 0; j < 8; ++j) m = fmaxf(m, v[it][j]);
    #pragma unroll
    for (int off = 32; off > 0; off >>= 1) m = fmaxf(m, __shfl_xor(m, off));

    float ssum = 0.0f;
    #pragma unroll
    for (int it = 0; it < 2; ++it)
        #pragma unroll
        for (int j = 0; j < 8; ++j)
            ssum += (v[it][j] > -1e37f) ? __expf(v[it][j] - m) : 0.0f;
    #pragma unroll
    for (int off = 32; off > 0; off >>= 1) ssum += __shfl_xor(ssum, off);

    if (ln == 0) stats[r0] = make_float2(m, 1.0f / ssum);
}

// ---------------------------------------------------------------------------
// proj5: fused cross-head projection + XCD-aware bijective remap. (unchanged)
// ---------------------------------------------------------------------------
template<bool SM>
__global__ __launch_bounds__(256, 4) void proj5(ushort* __restrict__ Lb,
                                                const ushort* __restrict__ Cmat,
                                                const ushort* __restrict__ Kmat,
                                                const float2* __restrict__ stats) {
    const int bid = blockIdx.y * 64 + blockIdx.x;
    const int xcd = bid & 7;
    const int idx = bid >> 3;                 // 0..511
    const int ty  = ((idx >> 6) << 3) + xcd;  // ty % 8 == xcd
    const int sx  = idx & 63;

    const int s0 = sx * 16;
    const int t0 = ty * 16;
    if (s0 > t0 + 15) return;

    __shared__ __align__(16) ushort Xs[16 * 648];   // 20736 B  [t][s:40][m]
    __shared__ __align__(16) float  Kp[16 * 260];   // 16640 B  [t][s:16][n]

    const int tid = threadIdx.x;
    const int wv = tid >> 6, ln = tid & 63;
    const int frow = ln & 15, quad = ln >> 4;

    #pragma unroll
    for (int it = 0; it < 4; ++it) {
        int slot = tid + it * 256;
        int c    = slot & 1;
        int row  = slot >> 1;
        int nn   = row >> 4, tl = row & 15;
        uint4 ld = *(const uint4*)(Lb + ((size_t)nn * T_DIM + t0 + tl) * S_DIM + s0 + c * 8);
        ushort u[8];
        u[0] = (ushort)(ld.x & 0xffff);  u[1] = (ushort)(ld.x >> 16);
        u[2] = (ushort)(ld.y & 0xffff);  u[3] = (ushort)(ld.y >> 16);
        u[4] = (ushort)(ld.z & 0xffff);  u[5] = (ushort)(ld.z >> 16);
        u[6] = (ushort)(ld.w & 0xffff);  u[7] = (ushort)(ld.w >> 16);
        if (SM) {
            const float2 ms = stats[nn * T_DIM + t0 + tl];
            const int tG = t0 + tl, sbase = s0 + c * 8;
            #pragma unroll
            for (int j = 0; j < 8; ++j) {
                float x = (sbase + j <= tG) ? __expf(b2f(u[j]) - ms.x) * ms.y : 0.0f;
                u[j] = f2b(x);
            }
        }
        ushort* xp = &Xs[tl * 648 + (c * 8) * 40 + nn];
        #pragma unroll
        for (int j = 0; j < 8; ++j) xp[j * 40] = u[j];
    }
    __syncthreads();

    #pragma unroll
    for (int mh = 0; mh < 2; ++mh) {
        #pragma unroll
        for (int k = 0; k < 4; ++k) {
            const int sl = wv * 4 + k;
            const short8 af = *(const short8*)(Kmat + (size_t)(s0 + sl) * 1024 + (mh * 16 + frow) * 32 + quad * 8);
            const short8 bf = *(const short8*)&Xs[frow * 648 + sl * 40 + quad * 8];
            floatx4 z = {0.f, 0.f, 0.f, 0.f};
            floatx4 d = __builtin_amdgcn_mfma_f32_16x16x32_bf16(af, bf, z, 0, 0, 0);
            *(floatx4*)&Kp[frow * 260 + sl * 16 + quad * 4] = d;
        }
        __syncthreads();

        #pragma unroll
        for (int i = 0; i < 4; ++i) {
            const int tl = wv * 4 + i;
            const int tg = t0 + tl;
            const short8 bf = *(const short8*)(Cmat + (size_t)tg * 1024 + (mh * 16 + frow) * 32 + quad * 8);
            const short8 af = *(const short8*)&Xs[tl * 648 + frow * 40 + quad * 8];
            floatx4 z = {0.f, 0.f, 0.f, 0.f};
            floatx4 d = __builtin_amdgcn_mfma_f32_16x16x32_bf16(af, bf, z, 0, 0, 0);
            float v[4];
            #pragma unroll
            for (int r = 0; r < 4; ++r) {
                const int sl = quad * 4 + r;
                float val = d[r] + Kp[tl * 260 + sl * 16 + frow];
                v[r] = (s0 + sl > tg) ? 0.0f : val;
            }
            uint2 stv;
            stv.x = (unsigned)pack_bf16(v[0], v[1]);
            stv.y = (unsigned)pack_bf16(v[2], v[3]);
            *(uint2*)&Lb[((size_t)(mh * 16 + frow) * T_DIM + tg) * S_DIM + s0 + quad * 4] = stv;
        }
        __syncthreads();
    }
}

// ---------------------------------------------------------------------------
// av4: O = P V via MFMA with B-fragment reuse. One block per (n, 32-t tile);
// each wave covers 2 16-row t-tiles so a step = 8 B-loads + 2 A-loads feeding
// 16 MFMAs (av3 was 9 loads : 8 MFMAs -- the load->MFMA dependency stall was
// the whole cost: MfmaUtil 3.5%, FETCH 21 MB, conflicts 0, VGPR 32 meant the
// compiler couldn't pipeline). acc=64 VGPR; launch_bounds(256,3) gives the
// compiler room to batch/prefetch loads. Grid (32 n, 32 tt) = 1024 blocks,
// big-tiles-first; XCD = n%8 keeps Vt (4 heads = 1 MB) L2-pinned.
// ---------------------------------------------------------------------------
__global__ __launch_bounds__(256, 3) void av4(const ushort* __restrict__ P,
                                              const ushort* __restrict__ Vt,
                                              float* __restrict__ O) {
    const int tid = threadIdx.x;
    const int wv = tid >> 6, ln = tid & 63;
    const int frow = ln & 15, quad = ln >> 4;
    const int n  = blockIdx.x;
    const int tt = 31 - blockIdx.y;      // big tiles first
    const int t0 = tt * 32;

    __shared__ ushort red[4][32][136];   // 34816 B bf16 partials

    const ushort* Pn  = P  + ((size_t)n * T_DIM + t0) * S_DIM;
    const ushort* Vtn = Vt + (size_t)n * D_HEAD * S_DIM;

    const int nsteps  = tt + 1;          // s <= t0+31  ->  (t0+32)/32 steps
    const int nclean0 = t0 >> 5;         // steps fully below diag for rows t0..t0+15
    const int nclean1 = (t0 + 16) >> 5;  // ... for rows t0+16..t0+31

    floatx4 acc[2][8] = {};
    for (int sb = wv; sb < nsteps; sb += 4) {
        const int scol = sb * 32 + quad * 8;
        short8 a0 = *(const short8*)(Pn + (size_t)frow * S_DIM + scol);
        short8 a1 = *(const short8*)(Pn + (size_t)(16 + frow) * S_DIM + scol);
        if (sb >= nclean0) {
            const int tg = t0 + frow;
            #pragma unroll
            for (int j = 0; j < 8; ++j)
                if (scol + j > tg) a0[j] = 0;
        }
        if (sb >= nclean1) {
            const int tg = t0 + 16 + frow;
            #pragma unroll
            for (int j = 0; j < 8; ++j)
                if (scol + j > tg) a1[j] = 0;
        }
        #pragma unroll
        for (int dc = 0; dc < 8; ++dc) {
            const short8 b = *(const short8*)(Vtn + (size_t)(dc * 16 + frow) * S_DIM + sb * 32 + quad * 8);
            acc[0][dc] = __builtin_amdgcn_mfma_f32_16x16x32_bf16(a0, b, acc[0][dc], 0, 0, 0);
            acc[1][dc] = __builtin_amdgcn_mfma_f32_16x16x32_bf16(a1, b, acc[1][dc], 0, 0, 0);
        }
    }

    #pragma unroll
    for (int tq = 0; tq < 2; ++tq)
        #pragma unroll
        for (int dc = 0; dc < 8; ++dc)
            #pragma unroll
            for (int r = 0; r < 4; ++r)
                red[wv][tq * 16 + quad * 4 + r][dc * 16 + frow] = f2b(acc[tq][dc][r]);
    __syncthreads();

    #pragma unroll
    for (int it = 0; it < 4; ++it) {
        int idx = tid + it * 256;
        int d4 = idx & 31, tr = idx >> 5;     // tr 0..31
        float4 v;
        v.x = b2f(red[0][tr][d4 * 4 + 0]) + b2f(red[1][tr][d4 * 4 + 0]) + b2f(red[2][tr][d4 * 4 + 0]) + b2f(red[3][tr][d4 * 4 + 0]);
        v.y = b2f(red[0][tr][d4 * 4 + 1]) + b2f(red[1][tr][d4 * 4 + 1]) + b2f(red[2][tr][d4 * 4 + 1]) + b2f(red[3][tr][d4 * 4 + 1]);
        v.z = b2f(red[0][tr][d4 * 4 + 2]) + b2f(red[1][tr][d4 * 4 + 2]) + b2f(red[2][tr][d4 * 4 + 2]) + b2f(red[3][tr][d4 * 4 + 2]);
        v.w = b2f(red[0][tr][d4 * 4 + 3]) + b2f(red[1][tr][d4 * 4 + 3]) + b2f(red[2][tr][d4 * 4 + 3]) + b2f(red[3][tr][d4 * 4 + 3]);
        *(float4*)&O[((size_t)n * T_DIM + t0 + tr) * D_HEAD + d4 * 4] = v;
    }
}

// ---------------------------------------------------------------------------
extern "C" void kernel_launch(void* const* d_in, const int* in_sizes, int n_in,
                              void* d_out, int out_size, void* d_ws, size_t ws_size,
                              hipStream_t stream) {
    const float* Q    = (const float*)d_in[0];
    const float* K    = (const float*)d_in[1];
    const float* V    = (const float*)d_in[2];
    const float* sw_pre  = (const float*)d_in[4];
    const float* qw1_pre = (const float*)d_in[5];
    const float* qw2_pre = (const float*)d_in[6];
    const float* kw1_pre = (const float*)d_in[7];
    const float* kw2_pre = (const float*)d_in[8];
    const float* qdd_pre = (const float*)d_in[9];
    const float* kdd_pre = (const float*)d_in[10];
    const float* sw_post  = (const float*)d_in[11];
    const float* qw1_post = (const float*)d_in[12];
    const float* qw2_post = (const float*)d_in[13];
    const float* kw1_post = (const float*)d_in[14];
    const float* kw2_post = (const float*)d_in[15];
    const float* qdd_post = (const float*)d_in[16];
    const float* kdd_post = (const float*)d_in[17];

    // ws layout: Lb 64 MB | Vt 8 MB | Qb 8 MB | Kb 8 MB  (= 88 MB total)
    ushort* Lb = (ushort*)d_ws;
    ushort* Vt = (ushort*)((char*)d_ws + (size_t)64 * 1024 * 1024);
    ushort* Qb = (ushort*)((char*)d_ws + (size_t)72 * 1024 * 1024);
    ushort* Kb = (ushort*)((char*)d_ws + (size_t)80 * 1024 * 1024);
    float*  O  = (float*)d_out;

    // d_out scratch (16 MB): mats in first 8 MB, softmax stats after.
    // Both fully consumed before av4 overwrites d_out.
    ushort* mats  = (ushort*)d_out;
    ushort* Cpre  = mats + 0 * 1024 * 1024;
    ushort* Kpre  = mats + 1 * 1024 * 1024;
    ushort* Cpost = mats + 2 * 1024 * 1024;
    ushort* Kpost = mats + 3 * 1024 * 1024;
    float2* stats = (float2*)((char*)d_out + (size_t)8 * 1024 * 1024);

    mat4_kernel<<<dim3(1024, 4), 256, 0, stream>>>(
        sw_pre, qw1_pre, qw2_pre, qdd_pre, kw1_pre, kw2_pre, kdd_pre,
        sw_post, qw1_post, qw2_post, qdd_post, kw1_post, kw2_post, kdd_post, mats);
    tobf16<<<dim3(2048), 256, 0, stream>>>(Q, K, Qb, Kb);
    vt_kernel<<<dim3(16, 32), 256, 0, stream>>>(V, Vt);

    qk2<<<dim3(8192), 256, 0, stream>>>(Qb, Kb, Lb);
    proj5<false><<<dim3(64, 64), 256, 0, stream>>>(Lb, Cpre, Kpre, nullptr);
    rowstat<<<dim3(8192), 256, 0, stream>>>(Lb, stats);
    proj5<true><<<dim3(64, 64), 256, 0, stream>>>(Lb, Cpost, Kpost, stats);
    av4<<<dim3(32, 32), 256, 0, stream>>>(Lb, Vt, O);
}

// Round 8
// 244.612 us; speedup vs baseline: 1.2419x; 1.0056x over previous
//
#include <hip/hip_runtime.h>
#include <hip/hip_bf16.h>
#include <cstdint>
#include <cstddef>

#define T_DIM 1024
#define S_DIM 1024
#define N_HEADS 32
#define D_HEAD 128

typedef __attribute__((ext_vector_type(8))) short short8;
typedef __attribute__((ext_vector_type(4))) float floatx4;

__device__ inline int pack_bf16(float a, float b) {
    __hip_bfloat162 h = __float22bfloat162_rn(make_float2(a, b));
    int r; __builtin_memcpy(&r, &h, 4); return r;
}
__device__ inline ushort f2b(float x) {
    __hip_bfloat16 h = __float2bfloat16(x);
    ushort u; __builtin_memcpy(&u, &h, 2); return u;
}
__device__ inline float b2f(ushort u) {
    unsigned int v = ((unsigned int)u) << 16;
    float f; __builtin_memcpy(&f, &v, 4); return f;
}

// ---------------------------------------------------------------------------
// tobf16: Qb/Kb bf16 <- Q/K fp32, straight elementwise. (unchanged)
// ---------------------------------------------------------------------------
__global__ __launch_bounds__(256) void tobf16(const float* __restrict__ Q,
                                              const float* __restrict__ K,
                                              ushort* __restrict__ Qb,
                                              ushort* __restrict__ Kb) {
    const size_t gid = (size_t)blockIdx.x * 256 + threadIdx.x;   // 0..524287
    #pragma unroll
    for (int j = 0; j < 2; ++j) {
        size_t i = gid + (size_t)j * 524288;                      // float4 idx
        float4 q = ((const float4*)Q)[i];
        int2 qp; qp.x = pack_bf16(q.x, q.y); qp.y = pack_bf16(q.z, q.w);
        ((int2*)Qb)[i] = qp;
        float4 k = ((const float4*)K)[i];
        int2 kp; kp.x = pack_bf16(k.x, k.y); kp.y = pack_bf16(k.z, k.w);
        ((int2*)Kb)[i] = kp;
    }
}

// ---------------------------------------------------------------------------
// Vt[n][d][s] bf16 <- V[n][s][d] fp32.  64s x 128d tile per block. (unchanged)
// ---------------------------------------------------------------------------
__global__ __launch_bounds__(256) void vt_kernel(const float* __restrict__ V,
                                                 ushort* __restrict__ Vt) {
    const int s0 = blockIdx.x * 64;
    const int n  = blockIdx.y;
    __shared__ float lds[128 * 65];

    const int tid = threadIdx.x;
    const float* Vn = V + ((size_t)n * S_DIM + s0) * D_HEAD;

    #pragma unroll
    for (int it = 0; it < 8; ++it) {
        int idx = tid + it * 256;
        int d4 = idx & 31, s = idx >> 5;
        float4 v = *(const float4*)(Vn + (size_t)s * D_HEAD + d4 * 4);
        lds[(d4 * 4 + 0) * 65 + s] = v.x;
        lds[(d4 * 4 + 1) * 65 + s] = v.y;
        lds[(d4 * 4 + 2) * 65 + s] = v.z;
        lds[(d4 * 4 + 3) * 65 + s] = v.w;
    }
    __syncthreads();

    ushort* Vtn = Vt + (size_t)n * D_HEAD * S_DIM;
    #pragma unroll
    for (int it = 0; it < 4; ++it) {
        int idx = tid + it * 256;
        int sg = idx & 7, d = idx >> 3;
        const float* src = &lds[d * 65 + sg * 8];
        int4 o;
        o.x = pack_bf16(src[0], src[1]);
        o.y = pack_bf16(src[2], src[3]);
        o.z = pack_bf16(src[4], src[5]);
        o.w = pack_bf16(src[6], src[7]);
        *(int4*)&Vtn[(size_t)d * S_DIM + s0 + sg * 8] = o;
    }
}

// ---------------------------------------------------------------------------
// qk2: logits (bf16) via MFMA, 64x64 causal tiles, bf16 inputs. (unchanged)
// ---------------------------------------------------------------------------
__global__ __launch_bounds__(256, 2) void qk2(const ushort* __restrict__ Qb,
                                              const ushort* __restrict__ Kb,
                                              ushort* __restrict__ Lb) {
    const int bid  = blockIdx.x;
    const int xcd  = bid & 7;
    const int i    = bid >> 3;             // 0..1023
    const int st   = i & 15;
    const int pair = (i >> 4) * 8 + xcd;   // 0..511 bijective
    const int n    = pair >> 4;
    const int tt   = pair & 15;
    if (st > tt) return;

    __shared__ int Qt[64 * 64];
    __shared__ int Kt[64 * 64];

    const int tid = threadIdx.x;
    const int wv = tid >> 6, ln = tid & 63;
    const int frow = ln & 15, quad = ln >> 4;

    const ushort* Qn = Qb + ((size_t)n * T_DIM + (size_t)tt * 64) * D_HEAD;
    const ushort* Kn = Kb + ((size_t)n * S_DIM + (size_t)st * 64) * D_HEAD;

    #pragma unroll
    for (int rep = 0; rep < 8; ++rep) {
        int idx = (tid + rep * 256) & 1023;
        int row = idx >> 4;
        int c   = idx & 15;                 // 16 B chunk = 8 bf16
        int kb  = c >> 2, qw = c & 3;
        int dst = row * 64 + kb * 16 + ((qw * 4) ^ (4 * (row & 3)));
        if (rep < 4) {
            uint4 v = *(const uint4*)(Qn + (size_t)row * D_HEAD + c * 8);
            *(uint4*)&Qt[dst] = v;
        } else {
            uint4 v = *(const uint4*)(Kn + (size_t)row * D_HEAD + c * 8);
            *(uint4*)&Kt[dst] = v;
        }
    }
    __syncthreads();

    const int swz = 4 * (frow & 3);
    floatx4 acc[4] = {};
    #pragma unroll
    for (int kb = 0; kb < 4; ++kb) {
        const short8 af = *(const short8*)&Qt[(wv * 16 + frow) * 64 + kb * 16 + ((quad * 4) ^ swz)];
        #pragma unroll
        for (int si = 0; si < 4; ++si) {
            const short8 bf = *(const short8*)&Kt[(si * 16 + frow) * 64 + kb * 16 + ((quad * 4) ^ swz)];
            acc[si] = __builtin_amdgcn_mfma_f32_16x16x32_bf16(af, bf, acc[si], 0, 0, 0);
        }
    }
    __syncthreads();                    // Qt dead -> reuse as output tile

    ushort* Ot = (ushort*)Qt;           // [64][72] bf16
    #pragma unroll
    for (int si = 0; si < 4; ++si)
        #pragma unroll
        for (int r = 0; r < 4; ++r)
            Ot[(wv * 16 + quad * 4 + r) * 72 + si * 16 + frow] = f2b(acc[si][r]);
    __syncthreads();

    #pragma unroll
    for (int it = 0; it < 2; ++it) {
        int idx = tid + it * 256;
        int row = idx >> 3, col = idx & 7;
        int4 v = *(const int4*)&Ot[row * 72 + col * 8];
        *(int4*)&Lb[((size_t)n * T_DIM + tt * 64 + row) * S_DIM + st * 64 + col * 8] = v;
    }
}

// ---------------------------------------------------------------------------
// Precompute all four 32x32 mixing-matrix families in one launch. (unchanged)
// ---------------------------------------------------------------------------
__global__ __launch_bounds__(256) void mat4_kernel(
        const float* __restrict__ sw_pre,  const float* __restrict__ qw1_pre,
        const float* __restrict__ qw2_pre, const float* __restrict__ qdd_pre,
        const float* __restrict__ kw1_pre, const float* __restrict__ kw2_pre,
        const float* __restrict__ kdd_pre,
        const float* __restrict__ sw_post,  const float* __restrict__ qw1_post,
        const float* __restrict__ qw2_post, const float* __restrict__ qdd_post,
        const float* __restrict__ kw1_post, const float* __restrict__ kw2_post,
        const float* __restrict__ kdd_post,
        ushort* __restrict__ mats) {
    const float *sw, *w1, *w2, *dd;
    float idadd;
    switch (blockIdx.y) {
        case 0:  sw = sw_pre;  w1 = qw1_pre;  w2 = qw2_pre;  dd = qdd_pre;  idadd = 1.0f; break;
        case 1:  sw = nullptr; w1 = kw1_pre;  w2 = kw2_pre;  dd = kdd_pre;  idadd = 0.0f; break;
        case 2:  sw = sw_post; w1 = qw1_post; w2 = qw2_post; dd = qdd_post; idadd = 1.0f; break;
        default: sw = nullptr; w1 = kw1_post; w2 = kw2_post; dd = kdd_post; idadd = 0.0f; break;
    }
    ushort* out = mats + (size_t)blockIdx.y * 1024 * 1024;

    const int t = blockIdx.x;
    const int tid = threadIdx.x;
    const int m = tid >> 3;
    const int n0 = (tid & 7) * 4;

    const float w2m0 = w2[t * 64 + m];
    const float w2m1 = w2[t * 64 + 32 + m];
    const float ddm  = dd[t * 32 + m];

    float v[4];
    #pragma unroll
    for (int j = 0; j < 4; ++j) {
        int n = n0 + j;
        float r = w1[t * 64 + n] * w2m0 + w1[t * 64 + 32 + n] * w2m1;
        if (sw) r += sw[n * 32 + m];
        if (n == m) r += idadd + ddm;
        v[j] = r;
    }
    int p0 = pack_bf16(v[0], v[1]);
    int p1 = pack_bf16(v[2], v[3]);
    int2 st = make_int2(p0, p1);
    *(int2*)&out[(size_t)t * 1024 + m * 32 + n0] = st;
}

// ---------------------------------------------------------------------------
// proj6: fused cross-head projection + XCD remap. SM=false additionally emits
// per-(row, 16s-tile) LSE partials (m, sumexp) straight from registers --
// replacing the full 33 MB rowstat re-read pass. pstat layout [t][sx][n]:
// the 16 quad-0 lanes per (wave, i, mh) write 128 contiguous bytes.
// SM=true applies softmax from stats2[t][n] during staging. (rest unchanged)
// ---------------------------------------------------------------------------
template<bool SM>
__global__ __launch_bounds__(256, 4) void proj6(ushort* __restrict__ Lb,
                                                const ushort* __restrict__ Cmat,
                                                const ushort* __restrict__ Kmat,
                                                const float2* __restrict__ stats2,
                                                float2* __restrict__ pstat) {
    const int bid = blockIdx.y * 64 + blockIdx.x;
    const int xcd = bid & 7;
    const int idx = bid >> 3;                 // 0..511
    const int ty  = ((idx >> 6) << 3) + xcd;  // ty % 8 == xcd
    const int sx  = idx & 63;

    const int s0 = sx * 16;
    const int t0 = ty * 16;
    if (s0 > t0 + 15) return;

    __shared__ __align__(16) ushort Xs[16 * 648];   // 20736 B  [t][s:40][m]
    __shared__ __align__(16) float  Kp[16 * 260];   // 16640 B  [t][s:16][n]

    const int tid = threadIdx.x;
    const int wv = tid >> 6, ln = tid & 63;
    const int frow = ln & 15, quad = ln >> 4;

    #pragma unroll
    for (int it = 0; it < 4; ++it) {
        int slot = tid + it * 256;
        int c    = slot & 1;
        int row  = slot >> 1;
        int nn   = row >> 4, tl = row & 15;
        uint4 ld = *(const uint4*)(Lb + ((size_t)nn * T_DIM + t0 + tl) * S_DIM + s0 + c * 8);
        ushort u[8];
        u[0] = (ushort)(ld.x & 0xffff);  u[1] = (ushort)(ld.x >> 16);
        u[2] = (ushort)(ld.y & 0xffff);  u[3] = (ushort)(ld.y >> 16);
        u[4] = (ushort)(ld.z & 0xffff);  u[5] = (ushort)(ld.z >> 16);
        u[6] = (ushort)(ld.w & 0xffff);  u[7] = (ushort)(ld.w >> 16);
        if (SM) {
            const float2 ms = stats2[(t0 + tl) * 32 + nn];
            const int tG = t0 + tl, sbase = s0 + c * 8;
            #pragma unroll
            for (int j = 0; j < 8; ++j) {
                float x = (sbase + j <= tG) ? __expf(b2f(u[j]) - ms.x) * ms.y : 0.0f;
                u[j] = f2b(x);
            }
        }
        ushort* xp = &Xs[tl * 648 + (c * 8) * 40 + nn];
        #pragma unroll
        for (int j = 0; j < 8; ++j) xp[j * 40] = u[j];
    }
    __syncthreads();

    #pragma unroll
    for (int mh = 0; mh < 2; ++mh) {
        #pragma unroll
        for (int k = 0; k < 4; ++k) {
            const int sl = wv * 4 + k;
            const short8 af = *(const short8*)(Kmat + (size_t)(s0 + sl) * 1024 + (mh * 16 + frow) * 32 + quad * 8);
            const short8 bf = *(const short8*)&Xs[frow * 648 + sl * 40 + quad * 8];
            floatx4 z = {0.f, 0.f, 0.f, 0.f};
            floatx4 d = __builtin_amdgcn_mfma_f32_16x16x32_bf16(af, bf, z, 0, 0, 0);
            *(floatx4*)&Kp[frow * 260 + sl * 16 + quad * 4] = d;
        }
        __syncthreads();

        #pragma unroll
        for (int i = 0; i < 4; ++i) {
            const int tl = wv * 4 + i;
            const int tg = t0 + tl;
            const short8 bf = *(const short8*)(Cmat + (size_t)tg * 1024 + (mh * 16 + frow) * 32 + quad * 8);
            const short8 af = *(const short8*)&Xs[tl * 648 + frow * 40 + quad * 8];
            floatx4 z = {0.f, 0.f, 0.f, 0.f};
            floatx4 d = __builtin_amdgcn_mfma_f32_16x16x32_bf16(af, bf, z, 0, 0, 0);
            float v[4];
            float lm = -INFINITY, lsum = 0.0f;
            #pragma unroll
            for (int r = 0; r < 4; ++r) {
                const int sl = quad * 4 + r;
                float val = d[r] + Kp[tl * 260 + sl * 16 + frow];
                const bool ok = (s0 + sl <= tg);
                v[r] = ok ? val : 0.0f;
                if (!SM) lm = fmaxf(lm, ok ? val : -INFINITY);
            }
            if (!SM) {
                #pragma unroll
                for (int r = 0; r < 4; ++r) {
                    const int sl = quad * 4 + r;
                    if (s0 + sl <= tg) lsum += __expf(v[r] - lm);
                }
                // LSE-merge across the 4 lanes sharing frow (quad bits 4,5)
                #pragma unroll
                for (int off = 16; off <= 32; off <<= 1) {
                    float om = __shfl_xor(lm, off);
                    float os = __shfl_xor(lsum, off);
                    float nm = fmaxf(lm, om);
                    float a = (lm > -1e37f) ? lsum * __expf(lm - nm) : 0.0f;
                    float b = (om > -1e37f) ? os   * __expf(om - nm) : 0.0f;
                    lm = nm; lsum = a + b;
                }
                if (quad == 0)
                    pstat[((size_t)tg * 64 + sx) * 32 + mh * 16 + frow] = make_float2(lm, lsum);
            }
            uint2 stv;
            stv.x = (unsigned)pack_bf16(v[0], v[1]);
            stv.y = (unsigned)pack_bf16(v[2], v[3]);
            *(uint2*)&Lb[((size_t)(mh * 16 + frow) * T_DIM + tg) * S_DIM + s0 + quad * 4] = stv;
        }
        __syncthreads();
    }
}

// ---------------------------------------------------------------------------
// statreduce: one block per t. Coalesced load of (ty+1)x32 LSE partials ->
// LDS -> 8-threads-per-head merge -> stats2[t][n] = (m, 1/sum).
// ---------------------------------------------------------------------------
__global__ __launch_bounds__(256) void statreduce(const float2* __restrict__ pstat,
                                                  float2* __restrict__ stats2) {
    const int t = blockIdx.x;
    const int ty = t >> 4;
    const int total = (ty + 1) * 32;
    __shared__ float sm[32][65];
    __shared__ float ss[32][65];

    const int tid = threadIdx.x;
    for (int base = 0; base < total; base += 256) {
        int idx = base + tid;
        if (idx < total) {
            float2 p = pstat[(size_t)t * 2048 + idx];   // [t][sx][n], idx = sx*32+n
            sm[idx & 31][idx >> 5] = p.x;
            ss[idx & 31][idx >> 5] = p.y;
        }
    }
    __syncthreads();

    const int n = tid >> 3, j = tid & 7;
    float m = -INFINITY, s = 0.0f;
    for (int sx = j; sx <= ty; sx += 8) {
        float om = sm[n][sx], os = ss[n][sx];
        float nm = fmaxf(m, om);
        float a = (m  > -1e37f) ? s  * __expf(m  - nm) : 0.0f;
        float b = (om > -1e37f) ? os * __expf(om - nm) : 0.0f;
        m = nm; s = a + b;
    }
    #pragma unroll
    for (int off = 1; off < 8; off <<= 1) {
        float om = __shfl_xor(m, off);
        float os = __shfl_xor(s, off);
        float nm = fmaxf(m, om);
        float a = (m  > -1e37f) ? s  * __expf(m  - nm) : 0.0f;
        float b = (om > -1e37f) ? os * __expf(om - nm) : 0.0f;
        m = nm; s = a + b;
    }
    if (j == 0) stats2[t * 32 + n] = make_float2(m, 1.0f / s);
}

// ---------------------------------------------------------------------------
// av4: O = P V via MFMA with B-fragment reuse. (unchanged)
// ---------------------------------------------------------------------------
__global__ __launch_bounds__(256, 3) void av4(const ushort* __restrict__ P,
                                              const ushort* __restrict__ Vt,
                                              float* __restrict__ O) {
    const int tid = threadIdx.x;
    const int wv = tid >> 6, ln = tid & 63;
    const int frow = ln & 15, quad = ln >> 4;
    const int n  = blockIdx.x;
    const int tt = 31 - blockIdx.y;      // big tiles first
    const int t0 = tt * 32;

    __shared__ ushort red[4][32][136];   // 34816 B bf16 partials

    const ushort* Pn  = P  + ((size_t)n * T_DIM + t0) * S_DIM;
    const ushort* Vtn = Vt + (size_t)n * D_HEAD * S_DIM;

    const int nsteps  = tt + 1;
    const int nclean0 = t0 >> 5;
    const int nclean1 = (t0 + 16) >> 5;

    floatx4 acc[2][8] = {};
    for (int sb = wv; sb < nsteps; sb += 4) {
        const int scol = sb * 32 + quad * 8;
        short8 a0 = *(const short8*)(Pn + (size_t)frow * S_DIM + scol);
        short8 a1 = *(const short8*)(Pn + (size_t)(16 + frow) * S_DIM + scol);
        if (sb >= nclean0) {
            const int tg = t0 + frow;
            #pragma unroll
            for (int j = 0; j < 8; ++j)
                if (scol + j > tg) a0[j] = 0;
        }
        if (sb >= nclean1) {
            const int tg = t0 + 16 + frow;
            #pragma unroll
            for (int j = 0; j < 8; ++j)
                if (scol + j > tg) a1[j] = 0;
        }
        #pragma unroll
        for (int dc = 0; dc < 8; ++dc) {
            const short8 b = *(const short8*)(Vtn + (size_t)(dc * 16 + frow) * S_DIM + sb * 32 + quad * 8);
            acc[0][dc] = __builtin_amdgcn_mfma_f32_16x16x32_bf16(a0, b, acc[0][dc], 0, 0, 0);
            acc[1][dc] = __builtin_amdgcn_mfma_f32_16x16x32_bf16(a1, b, acc[1][dc], 0, 0, 0);
        }
    }

    #pragma unroll
    for (int tq = 0; tq < 2; ++tq)
        #pragma unroll
        for (int dc = 0; dc < 8; ++dc)
            #pragma unroll
            for (int r = 0; r < 4; ++r)
                red[wv][tq * 16 + quad * 4 + r][dc * 16 + frow] = f2b(acc[tq][dc][r]);
    __syncthreads();

    #pragma unroll
    for (int it = 0; it < 4; ++it) {
        int idx = tid + it * 256;
        int d4 = idx & 31, tr = idx >> 5;     // tr 0..31
        float4 v;
        v.x = b2f(red[0][tr][d4 * 4 + 0]) + b2f(red[1][tr][d4 * 4 + 0]) + b2f(red[2][tr][d4 * 4 + 0]) + b2f(red[3][tr][d4 * 4 + 0]);
        v.y = b2f(red[0][tr][d4 * 4 + 1]) + b2f(red[1][tr][d4 * 4 + 1]) + b2f(red[2][tr][d4 * 4 + 1]) + b2f(red[3][tr][d4 * 4 + 1]);
        v.z = b2f(red[0][tr][d4 * 4 + 2]) + b2f(red[1][tr][d4 * 4 + 2]) + b2f(red[2][tr][d4 * 4 + 2]) + b2f(red[3][tr][d4 * 4 + 2]);
        v.w = b2f(red[0][tr][d4 * 4 + 3]) + b2f(red[1][tr][d4 * 4 + 3]) + b2f(red[2][tr][d4 * 4 + 3]) + b2f(red[3][tr][d4 * 4 + 3]);
        *(float4*)&O[((size_t)n * T_DIM + t0 + tr) * D_HEAD + d4 * 4] = v;
    }
}

// ---------------------------------------------------------------------------
extern "C" void kernel_launch(void* const* d_in, const int* in_sizes, int n_in,
                              void* d_out, int out_size, void* d_ws, size_t ws_size,
                              hipStream_t stream) {
    const float* Q    = (const float*)d_in[0];
    const float* K    = (const float*)d_in[1];
    const float* V    = (const float*)d_in[2];
    const float* sw_pre  = (const float*)d_in[4];
    const float* qw1_pre = (const float*)d_in[5];
    const float* qw2_pre = (const float*)d_in[6];
    const float* kw1_pre = (const float*)d_in[7];
    const float* kw2_pre = (const float*)d_in[8];
    const float* qdd_pre = (const float*)d_in[9];
    const float* kdd_pre = (const float*)d_in[10];
    const float* sw_post  = (const float*)d_in[11];
    const float* qw1_post = (const float*)d_in[12];
    const float* qw2_post = (const float*)d_in[13];
    const float* kw1_post = (const float*)d_in[14];
    const float* kw2_post = (const float*)d_in[15];
    const float* qdd_post = (const float*)d_in[16];
    const float* kdd_post = (const float*)d_in[17];

    // ws layout: Lb 64 MB | Vt 8 MB | Qb 8 MB | Kb 8 MB | pstat 16 MB (=104 MB)
    ushort* Lb = (ushort*)d_ws;
    ushort* Vt = (ushort*)((char*)d_ws + (size_t)64 * 1024 * 1024);
    ushort* Qb = (ushort*)((char*)d_ws + (size_t)72 * 1024 * 1024);
    ushort* Kb = (ushort*)((char*)d_ws + (size_t)80 * 1024 * 1024);
    float2* pstat = (float2*)((char*)d_ws + (size_t)96 * 1024 * 1024);
    float*  O  = (float*)d_out;

    // d_out scratch (16 MB): mats in first 8 MB, stats2 after.
    // Both fully consumed before av4 overwrites d_out.
    ushort* mats  = (ushort*)d_out;
    ushort* Cpre  = mats + 0 * 1024 * 1024;
    ushort* Kpre  = mats + 1 * 1024 * 1024;
    ushort* Cpost = mats + 2 * 1024 * 1024;
    ushort* Kpost = mats + 3 * 1024 * 1024;
    float2* stats2 = (float2*)((char*)d_out + (size_t)8 * 1024 * 1024);

    mat4_kernel<<<dim3(1024, 4), 256, 0, stream>>>(
        sw_pre, qw1_pre, qw2_pre, qdd_pre, kw1_pre, kw2_pre, kdd_pre,
        sw_post, qw1_post, qw2_post, qdd_post, kw1_post, kw2_post, kdd_post, mats);
    tobf16<<<dim3(2048), 256, 0, stream>>>(Q, K, Qb, Kb);
    vt_kernel<<<dim3(16, 32), 256, 0, stream>>>(V, Vt);

    qk2<<<dim3(8192), 256, 0, stream>>>(Qb, Kb, Lb);
    proj6<false><<<dim3(64, 64), 256, 0, stream>>>(Lb, Cpre, Kpre, nullptr, pstat);
    statreduce<<<dim3(1024), 256, 0, stream>>>(pstat, stats2);
    proj6<true><<<dim3(64, 64), 256, 0, stream>>>(Lb, Cpost, Kpost, stats2, nullptr);
    av4<<<dim3(32, 32), 256, 0, stream>>>(Lb, Vt, O);
}